// Round 1
// baseline (484.669 us; speedup 1.0000x reference)
//
#include <hip/hip_runtime.h>
#include <hip/hip_bf16.h>
#include <math.h>

// Problem constants
#define D_   1024
#define HD_  64
#define NH_  16
#define H_   16
#define KH_  8
#define NT_  128      // tokens per chunk (N)
#define E_   4096
#define RE_  4
#define DE_  4
#define ET_  16
#define S_   2048
#define T_   2048
#define BC_  16
#define EPS_ 1e-5f

typedef short s16x8 __attribute__((ext_vector_type(8)));
typedef float f32x4 __attribute__((ext_vector_type(4)));

__device__ __forceinline__ unsigned short f2bf(float f) {
    union { float f; unsigned int u; } v; v.f = f;
    unsigned int r = (v.u + 0x7fffu + ((v.u >> 16) & 1u)) >> 16;  // RNE
    return (unsigned short)r;
}
__device__ __forceinline__ float bf2f(unsigned short u) {
    union { unsigned int i; float f; } v;
    v.i = ((unsigned int)u) << 16;
    return v.f;
}

// ---------------------------------------------------------------------------
// rmsnorm (fp32 out)
// ---------------------------------------------------------------------------
__global__ __launch_bounds__(256) void rmsnorm_kernel(
    const float* __restrict__ x, const float* __restrict__ w,
    float* __restrict__ out)
{
    int row = blockIdx.x, tid = threadIdx.x;
    __shared__ float sred[4];
    float4 v = ((const float4*)(x + (size_t)row * D_))[tid];
    float ss = v.x*v.x + v.y*v.y + v.z*v.z + v.w*v.w;
#pragma unroll
    for (int off = 32; off > 0; off >>= 1) ss += __shfl_xor(ss, off);
    if ((tid & 63) == 0) sred[tid >> 6] = ss;
    __syncthreads();
    float tot = sred[0] + sred[1] + sred[2] + sred[3];
    float scale = rsqrtf(tot * (1.0f / D_) + EPS_);
    float4 wv = ((const float4*)w)[tid];
    float4 o;
    o.x = v.x * scale * wv.x;
    o.y = v.y * scale * wv.y;
    o.z = v.z * scale * wv.z;
    o.w = v.w * scale * wv.w;
    ((float4*)(out + (size_t)row * D_))[tid] = o;
}

// rmsnorm (bf16 out)
__global__ __launch_bounds__(256) void rmsnorm_bf16_kernel(
    const float* __restrict__ x, const float* __restrict__ w,
    unsigned short* __restrict__ out)
{
    int row = blockIdx.x, tid = threadIdx.x;
    __shared__ float sred[4];
    float4 v = ((const float4*)(x + (size_t)row * D_))[tid];
    float ss = v.x*v.x + v.y*v.y + v.z*v.z + v.w*v.w;
#pragma unroll
    for (int off = 32; off > 0; off >>= 1) ss += __shfl_xor(ss, off);
    if ((tid & 63) == 0) sred[tid >> 6] = ss;
    __syncthreads();
    float tot = sred[0] + sred[1] + sred[2] + sred[3];
    float scale = rsqrtf(tot * (1.0f / D_) + EPS_);
    float4 wv = ((const float4*)w)[tid];
    ushort4 o;
    o.x = f2bf(v.x * scale * wv.x);
    o.y = f2bf(v.y * scale * wv.y);
    o.z = f2bf(v.z * scale * wv.z);
    o.w = f2bf(v.w * scale * wv.w);
    *(ushort4*)(out + (size_t)row * D_ + tid * 4) = o;
}

// rmsnorm dual: fp32 out + bf16 out
__global__ __launch_bounds__(256) void rmsnorm_dual_kernel(
    const float* __restrict__ x, const float* __restrict__ w,
    float* __restrict__ out, unsigned short* __restrict__ outb)
{
    int row = blockIdx.x, tid = threadIdx.x;
    __shared__ float sred[4];
    float4 v = ((const float4*)(x + (size_t)row * D_))[tid];
    float ss = v.x*v.x + v.y*v.y + v.z*v.z + v.w*v.w;
#pragma unroll
    for (int off = 32; off > 0; off >>= 1) ss += __shfl_xor(ss, off);
    if ((tid & 63) == 0) sred[tid >> 6] = ss;
    __syncthreads();
    float tot = sred[0] + sred[1] + sred[2] + sred[3];
    float scale = rsqrtf(tot * (1.0f / D_) + EPS_);
    float4 wv = ((const float4*)w)[tid];
    float4 o;
    o.x = v.x * scale * wv.x;
    o.y = v.y * scale * wv.y;
    o.z = v.z * scale * wv.z;
    o.w = v.w * scale * wv.w;
    ((float4*)(out + (size_t)row * D_))[tid] = o;
    ushort4 ob;
    ob.x = f2bf(o.x); ob.y = f2bf(o.y); ob.z = f2bf(o.z); ob.w = f2bf(o.w);
    *(ushort4*)(outb + (size_t)row * D_ + tid * 4) = ob;
}

// ---------------------------------------------------------------------------
// convert + transpose: src [R][Ncols] fp32  ->  dst [Ncols][R] bf16
// ---------------------------------------------------------------------------
__global__ __launch_bounds__(256) void convt_kernel(
    const float* __restrict__ src, unsigned short* __restrict__ dst,
    int R, int Ncols)
{
    __shared__ float tile[32][33];
    int bx = blockIdx.x * 32;   // col block
    int by = blockIdx.y * 32;   // row block
    int tx = threadIdx.x & 31, ty = threadIdx.x >> 5;  // 8 rows per pass
#pragma unroll
    for (int rr = 0; rr < 32; rr += 8)
        tile[ty + rr][tx] = src[(size_t)(by + ty + rr) * Ncols + bx + tx];
    __syncthreads();
#pragma unroll
    for (int rr = 0; rr < 32; rr += 8)
        dst[(size_t)(bx + ty + rr) * R + by + tx] = f2bf(tile[tx][ty + rr]);
}

// ---------------------------------------------------------------------------
// bf16 transpose: vhb [NH][S][HD] -> vhT [NH][HD][S]
// ---------------------------------------------------------------------------
__global__ __launch_bounds__(256) void transpose_v_kernel(
    const unsigned short* __restrict__ src, unsigned short* __restrict__ dst)
{
    __shared__ unsigned short tile[32][34];
    int h  = blockIdx.z;
    int d0 = blockIdx.x * 32;   // HD/32 = 2
    int s0 = blockIdx.y * 32;   // S/32 = 64
    int tx = threadIdx.x & 31, ty = threadIdx.x >> 5;
    const unsigned short* sp = src + ((size_t)h * S_ + s0) * HD_ + d0;
#pragma unroll
    for (int rr = 0; rr < 32; rr += 8)
        tile[ty + rr][tx] = sp[(size_t)(ty + rr) * HD_ + tx];
    __syncthreads();
    unsigned short* dp = dst + ((size_t)h * HD_ + d0) * S_ + s0;
#pragma unroll
    for (int rr = 0; rr < 32; rr += 8)
        dp[(size_t)(ty + rr) * S_ + tx] = tile[tx][ty + rr];
}

// ---------------------------------------------------------------------------
// MFMA GEMM: C[M,N] fp32 = A[M,K] bf16 @ Bt[N,K] bf16 (+ res fp32)
// ---------------------------------------------------------------------------
template <int WITH_RES>
__global__ __launch_bounds__(256) void mfma_gemm_kernel(
    const unsigned short* __restrict__ A, const unsigned short* __restrict__ Bt,
    const float* __restrict__ res, float* __restrict__ C,
    int M, int N, int K)
{
    __shared__ short As[128][40];
    __shared__ short Bs[128][40];
    int tid = threadIdx.x;
    int wave = tid >> 6, lane = tid & 63;
    int ml = lane & 15, q = lane >> 4;
    int wr = wave >> 1, wc = wave & 1;
    int bm = blockIdx.y * 128, bn = blockIdx.x * 128;
    int srow = tid >> 2;
    int scol = (tid & 3) * 8;

    f32x4 acc[4][4];
#pragma unroll
    for (int i = 0; i < 4; i++)
#pragma unroll
        for (int j = 0; j < 4; j++) acc[i][j] = (f32x4){0.f, 0.f, 0.f, 0.f};

    for (int k0 = 0; k0 < K; k0 += 32) {
        int4 a0 = *(const int4*)(A + (size_t)(bm + srow) * K + k0 + scol);
        int4 a1 = *(const int4*)(A + (size_t)(bm + srow + 64) * K + k0 + scol);
        int4 b0 = *(const int4*)(Bt + (size_t)(bn + srow) * K + k0 + scol);
        int4 b1 = *(const int4*)(Bt + (size_t)(bn + srow + 64) * K + k0 + scol);
        __syncthreads();
        *(int4*)(&As[srow][scol]) = a0;
        *(int4*)(&As[srow + 64][scol]) = a1;
        *(int4*)(&Bs[srow][scol]) = b0;
        *(int4*)(&Bs[srow + 64][scol]) = b1;
        __syncthreads();

        s16x8 af[4], bf[4];
#pragma unroll
        for (int i = 0; i < 4; i++)
            af[i] = *(const s16x8*)(&As[wr * 64 + i * 16 + ml][q * 8]);
#pragma unroll
        for (int j = 0; j < 4; j++)
            bf[j] = *(const s16x8*)(&Bs[wc * 64 + j * 16 + ml][q * 8]);
#pragma unroll
        for (int i = 0; i < 4; i++)
#pragma unroll
            for (int j = 0; j < 4; j++)
                acc[i][j] = __builtin_amdgcn_mfma_f32_16x16x32_bf16(
                    af[i], bf[j], acc[i][j], 0, 0, 0);
    }

#pragma unroll
    for (int i = 0; i < 4; i++) {
#pragma unroll
        for (int j = 0; j < 4; j++) {
            int col = bn + wc * 64 + j * 16 + ml;
#pragma unroll
            for (int r = 0; r < 4; r++) {
                int row = bm + wr * 64 + i * 16 + q * 4 + r;
                float v = acc[i][j][r];
                if (WITH_RES) v += res[(size_t)row * N + col];
                C[(size_t)row * N + col] = v;
            }
        }
    }
}

// ---------------------------------------------------------------------------
// qkv prep: split qkv into per-head (NH,S,HD) bf16 q/k/v with l2norm + rope.
// ---------------------------------------------------------------------------
__global__ __launch_bounds__(64) void qkv_prep_kernel(
    const float* __restrict__ qkv, unsigned short* __restrict__ qh,
    unsigned short* __restrict__ khb, unsigned short* __restrict__ vhb)
{
    int bid = blockIdx.x;
    int s = bid / NH_, h = bid % NH_;
    int lane = threadIdx.x;

    size_t qoff = (size_t)s * (3 * D_) + h * HD_ + lane;
    float qv = qkv[qoff];
    float kv = qkv[qoff + D_];
    float vv = qkv[qoff + 2 * D_];

    float sq = qv * qv, sk = kv * kv;
#pragma unroll
    for (int off = 32; off > 0; off >>= 1) {
        sq += __shfl_xor(sq, off);
        sk += __shfl_xor(sk, off);
    }
    qv /= fmaxf(sqrtf(sq), EPS_);
    kv /= fmaxf(sqrtf(sk), EPS_);

    int j = lane & 31;
    float sign = (lane < 32) ? 1.0f : -1.0f;
    float inv_freq = exp2f((float)j * (-13.287712379549449f / 32.0f));
    float f = (float)s * inv_freq;
    float sn, cs;
    sincosf(f, &sn, &cs);
    float qo = __shfl_xor(qv, 32);
    float ko = __shfl_xor(kv, 32);
    qv = qv * cs + sign * qo * sn;
    kv = kv * cs + sign * ko * sn;

    size_t o = ((size_t)h * S_ + s) * HD_ + lane;
    qh[o]  = f2bf(qv * 0.125f);   // fold 1/sqrt(64)
    khb[o] = f2bf(kv);
    vhb[o] = f2bf(vv);
}

// ---------------------------------------------------------------------------
// MFMA bf16 flash attention, barrier-free.
//   grid = (S_/64) * NH_ blocks; blockIdx = t*16 + h  (same-h blocks land on
//   the same XCD under %8 round-robin -> head's K/V stays in one L2).
//   Q/K/V^T fragments come straight from global (L2-resident, <=512KB/head);
//   only LDS use is a tiny per-wave P-exchange buffer (intra-wave, no syncs).
// ---------------------------------------------------------------------------
__global__ __launch_bounds__(256) void flash_attn_mfma_kernel(
    const unsigned short* __restrict__ qh, const unsigned short* __restrict__ khb,
    const unsigned short* __restrict__ vhT, unsigned short* __restrict__ aob)
{
    __shared__ __align__(16) short Ps[4][16][72];   // [wave][qrow][kcol]
    int h = blockIdx.x & 15;
    int t = blockIdx.x >> 4;
    int tid = threadIdx.x;
    int wq = tid >> 6;
    int lane = tid & 63;
    int ml = lane & 15, quad = lane >> 4;
    const unsigned short* Qb = qh  + (size_t)h * S_ * HD_;
    const unsigned short* Kb = khb + (size_t)h * S_ * HD_;
    const unsigned short* Vt = vhT + (size_t)h * HD_ * S_;

    int q0 = t * 64;
    int qrow = q0 + wq * 16 + ml;
    s16x8 aq0 = *(const s16x8*)(Qb + (size_t)qrow * HD_ + quad * 8);
    s16x8 aq1 = *(const s16x8*)(Qb + (size_t)qrow * HD_ + 32 + quad * 8);

    float m[4], l[4];
    f32x4 o[4];
#pragma unroll
    for (int r = 0; r < 4; r++) { m[r] = -INFINITY; l[r] = 0.f; }
#pragma unroll
    for (int nb = 0; nb < 4; nb++) o[nb] = (f32x4){0.f, 0.f, 0.f, 0.f};

    for (int kt = 0; kt <= t; kt++) {
        int k0 = kt * 64;

        f32x4 s[4];
#pragma unroll
        for (int nb = 0; nb < 4; nb++) s[nb] = (f32x4){0.f, 0.f, 0.f, 0.f};
#pragma unroll
        for (int nb = 0; nb < 4; nb++) {
            const unsigned short* kp =
                Kb + (size_t)(k0 + nb * 16 + ml) * HD_ + quad * 8;
            s16x8 b0 = *(const s16x8*)kp;
            s16x8 b1 = *(const s16x8*)(kp + 32);
            s[nb] = __builtin_amdgcn_mfma_f32_16x16x32_bf16(aq0, b0, s[nb], 0, 0, 0);
            s[nb] = __builtin_amdgcn_mfma_f32_16x16x32_bf16(aq1, b1, s[nb], 0, 0, 0);
        }

        float sv[4][4];
#pragma unroll
        for (int nb = 0; nb < 4; nb++)
#pragma unroll
            for (int r = 0; r < 4; r++) {
                float v = s[nb][r];
                if (kt == t && (nb * 16 + ml) > (wq * 16 + quad * 4 + r))
                    v = -1e30f;
                sv[nb][r] = v;
            }
#pragma unroll
        for (int r = 0; r < 4; r++) {
            float rm = fmaxf(fmaxf(sv[0][r], sv[1][r]),
                             fmaxf(sv[2][r], sv[3][r]));
#pragma unroll
            for (int off = 1; off < 16; off <<= 1)
                rm = fmaxf(rm, __shfl_xor(rm, off));
            float mn = fmaxf(m[r], rm);
            float corr = __expf(m[r] - mn);
            m[r] = mn;
            float rs = 0.f;
#pragma unroll
            for (int nb = 0; nb < 4; nb++) {
                float pe = __expf(sv[nb][r] - mn);
                sv[nb][r] = pe;
                rs += pe;
            }
#pragma unroll
            for (int off = 1; off < 16; off <<= 1)
                rs += __shfl_xor(rs, off);
            l[r] = l[r] * corr + rs;
#pragma unroll
            for (int nb = 0; nb < 4; nb++) o[nb][r] *= corr;
        }

        // intra-wave P exchange (C-layout -> A-fragment layout); no barriers:
        // each wave touches only its own Ps[wq] slice, LDS ops within a wave
        // complete in order.
#pragma unroll
        for (int nb = 0; nb < 4; nb++)
#pragma unroll
            for (int r = 0; r < 4; r++)
                Ps[wq][quad * 4 + r][nb * 16 + ml] = (short)f2bf(sv[nb][r]);

        s16x8 ap0 = *(const s16x8*)(&Ps[wq][ml][quad * 8]);
        s16x8 ap1 = *(const s16x8*)(&Ps[wq][ml][32 + quad * 8]);
#pragma unroll
        for (int nb = 0; nb < 4; nb++) {
            const unsigned short* vp =
                Vt + (size_t)(nb * 16 + ml) * S_ + k0 + quad * 8;
            s16x8 b0 = *(const s16x8*)vp;
            s16x8 b1 = *(const s16x8*)(vp + 32);
            o[nb] = __builtin_amdgcn_mfma_f32_16x16x32_bf16(ap0, b0, o[nb], 0, 0, 0);
            o[nb] = __builtin_amdgcn_mfma_f32_16x16x32_bf16(ap1, b1, o[nb], 0, 0, 0);
        }
    }

#pragma unroll
    for (int r = 0; r < 4; r++) {
        float inv = 1.0f / l[r];
        int row = q0 + wq * 16 + quad * 4 + r;
#pragma unroll
        for (int nb = 0; nb < 4; nb++)
            aob[(size_t)row * D_ + h * HD_ + nb * 16 + ml] =
                f2bf(o[nb][r] * inv);
    }
}

// ---------------------------------------------------------------------------
// gather keys columns into compact bf16 buffer.
// block (pair, kh) -> kgath[pair][kh][0..1024) bf16
// Per chunk c, row n = e*8+kh at offset (c*128+n)*1024: contiguous Bt layout.
// ---------------------------------------------------------------------------
__global__ __launch_bounds__(256) void gather_keys_kernel(
    const float* __restrict__ keys, const int* __restrict__ indices,
    unsigned short* __restrict__ kgath)
{
    int bid = blockIdx.x;
    int pair = bid >> 3, kh = bid & 7;
    int idx = indices[pair];
    int tid = threadIdx.x;
    const float* kp = keys + (size_t)kh * D_ * E_ + idx;
    int d = tid * 4;
    ushort4 o;
    o.x = f2bf(kp[(size_t)(d + 0) * E_]);
    o.y = f2bf(kp[(size_t)(d + 1) * E_]);
    o.z = f2bf(kp[(size_t)(d + 2) * E_]);
    o.w = f2bf(kp[(size_t)(d + 3) * E_]);
    *(ushort4*)(kgath + ((size_t)pair * KH_ + kh) * D_ + d) = o;
}

// ---------------------------------------------------------------------------
// expert score GEMM (one block per chunk): msbuf[c][128 t][128 n] fp32 =
//   xfb[c*128..][1024] @ kgath[c*128..][1024]^T   (n = e*8+kh)
// ---------------------------------------------------------------------------
__global__ __launch_bounds__(256) void score_gemm_kernel(
    const unsigned short* __restrict__ xfb, const unsigned short* __restrict__ kgath,
    float* __restrict__ msbuf)
{
    __shared__ short As[128][40];
    __shared__ short Bs[128][40];
    int c = blockIdx.x;
    const unsigned short* A  = xfb   + (size_t)c * 128 * D_;
    const unsigned short* Bt = kgath + (size_t)c * 128 * D_;
    int tid = threadIdx.x;
    int wave = tid >> 6, lane = tid & 63;
    int ml = lane & 15, q = lane >> 4;
    int wr = wave >> 1, wc = wave & 1;
    int srow = tid >> 2;
    int scol = (tid & 3) * 8;

    f32x4 acc[4][4];
#pragma unroll
    for (int i = 0; i < 4; i++)
#pragma unroll
        for (int j = 0; j < 4; j++) acc[i][j] = (f32x4){0.f, 0.f, 0.f, 0.f};

    for (int k0 = 0; k0 < D_; k0 += 32) {
        int4 a0 = *(const int4*)(A + (size_t)srow * D_ + k0 + scol);
        int4 a1 = *(const int4*)(A + (size_t)(srow + 64) * D_ + k0 + scol);
        int4 b0 = *(const int4*)(Bt + (size_t)srow * D_ + k0 + scol);
        int4 b1 = *(const int4*)(Bt + (size_t)(srow + 64) * D_ + k0 + scol);
        __syncthreads();
        *(int4*)(&As[srow][scol]) = a0;
        *(int4*)(&As[srow + 64][scol]) = a1;
        *(int4*)(&Bs[srow][scol]) = b0;
        *(int4*)(&Bs[srow + 64][scol]) = b1;
        __syncthreads();

        s16x8 af[4], bf[4];
#pragma unroll
        for (int i = 0; i < 4; i++)
            af[i] = *(const s16x8*)(&As[wr * 64 + i * 16 + ml][q * 8]);
#pragma unroll
        for (int j = 0; j < 4; j++)
            bf[j] = *(const s16x8*)(&Bs[wc * 64 + j * 16 + ml][q * 8]);
#pragma unroll
        for (int i = 0; i < 4; i++)
#pragma unroll
            for (int j = 0; j < 4; j++)
                acc[i][j] = __builtin_amdgcn_mfma_f32_16x16x32_bf16(
                    af[i], bf[j], acc[i][j], 0, 0, 0);
    }

    float* out = msbuf + (size_t)c * 128 * 128;
#pragma unroll
    for (int i = 0; i < 4; i++)
#pragma unroll
        for (int j = 0; j < 4; j++) {
            int col = wc * 64 + j * 16 + ml;
#pragma unroll
            for (int r = 0; r < 4; r++) {
                int row = wr * 64 + i * 16 + q * 4 + r;
                out[(size_t)row * 128 + col] = acc[i][j][r];
            }
        }
}

// ---------------------------------------------------------------------------
// gather sp0/sp1/hp per (chunk, e, h) into coalesced spbuf[c][3][256]
// ---------------------------------------------------------------------------
__global__ __launch_bounds__(256) void gather_sp_kernel(
    const float* __restrict__ score_probs, const float* __restrict__ head_probs,
    const int* __restrict__ indices, float* __restrict__ spbuf)
{
    int c = blockIdx.x, tid = threadIdx.x;
    int e = tid >> 4, h = tid & 15;
    int idx = indices[c * ET_ + e];
    int r = e >> 2;   // e / DE_
    float v0 = score_probs[((size_t)(0 * RE_ + r) * E_ + idx) * H_ + h];
    float v1 = score_probs[((size_t)(1 * RE_ + r) * E_ + idx) * H_ + h];
    float v2 = head_probs[((size_t)r * E_ + idx) * H_ + h];
    float* sp = spbuf + (size_t)c * 3 * 256;
    sp[tid] = v0;
    sp[256 + tid] = v1;
    sp[512 + tid] = v2;
}

// ---------------------------------------------------------------------------
// MoE with rank-1 experts + fused combine-weight computation.
// One block per token; prologue computes sw[e] from msbuf/scores/spbuf.
// ---------------------------------------------------------------------------
__global__ __launch_bounds__(256) void moe_kernel(
    const float* __restrict__ xf, const float* __restrict__ xfi,
    const int* __restrict__ indices, const float* __restrict__ msbuf,
    const float* __restrict__ scores, const float* __restrict__ spbuf,
    const float* __restrict__ experts, float* __restrict__ out)
{
    int t = blockIdx.x, tid = threadIdx.x;
    int c = t / NT_;
    __shared__ int sidx[ET_];
    __shared__ float sw[ET_];
    __shared__ float r0[4], r1[4];
    if (tid < ET_) sidx[tid] = indices[c * ET_ + tid];
    // ---- combine weights: thread = (e = tid>>4, h = tid&15) ----
    {
        int e = tid >> 4, h = tid & 15;
        float ms = msbuf[(size_t)t * 128 + e * 8 + (h >> 1)];
        float sc = scores[(size_t)t * (ET_ * H_) + tid];
        const float* sp = spbuf + (size_t)c * 3 * 256;
        float z = sp[tid] * ms + sp[256 + tid] * sc;
        float term = sp[512 + tid] / (1.0f + __expf(-z));
#pragma unroll
        for (int off = 1; off < 16; off <<= 1)
            term += __shfl_xor(term, off);
        if (h == 0) sw[e] = term;
    }
    float4 xv = ((const float4*)(xf + (size_t)t * D_))[tid];
    float acc[4] = {0.f, 0.f, 0.f, 0.f};
    __syncthreads();
    for (int e = 0; e < ET_; e++) {
        int idx = sidx[e];
        size_t base = (size_t)idx * D_;
        float4 w0 = *(const float4*)(experts + base + tid * 4);
        float4 w1 = *(const float4*)(experts + (size_t)E_ * D_ + base + tid * 4);
        float p0 = xv.x * w0.x + xv.y * w0.y + xv.z * w0.z + xv.w * w0.w;
        float p1 = xv.x * w1.x + xv.y * w1.y + xv.z * w1.z + xv.w * w1.w;
#pragma unroll
        for (int off = 32; off > 0; off >>= 1) {
            p0 += __shfl_xor(p0, off);
            p1 += __shfl_xor(p1, off);
        }
        if ((tid & 63) == 0) { r0[tid >> 6] = p0; r1[tid >> 6] = p1; }
        __syncthreads();
        float h0 = r0[0] + r0[1] + r0[2] + r0[3];
        float h1 = r1[0] + r1[1] + r1[2] + r1[3];
        __syncthreads();
        float act = h0 / (1.0f + __expf(-h0)) * h1 * sw[e];
        float4 w2 = *(const float4*)(experts + (size_t)2 * E_ * D_ + base + tid * 4);
        acc[0] += act * w2.x;
        acc[1] += act * w2.y;
        acc[2] += act * w2.z;
        acc[3] += act * w2.w;
    }
    size_t o = (size_t)t * D_ + tid * 4;
    float4 rv = *(const float4*)(xfi + o);
    float4 ov;
    ov.x = acc[0] + rv.x;
    ov.y = acc[1] + rv.y;
    ov.z = acc[2] + rv.z;
    ov.w = acc[3] + rv.w;
    *(float4*)(out + o) = ov;
}

// ---------------------------------------------------------------------------
extern "C" void kernel_launch(void* const* d_in, const int* in_sizes, int n_in,
                              void* d_out, int out_size, void* d_ws, size_t ws_size,
                              hipStream_t stream)
{
    (void)in_sizes; (void)n_in; (void)out_size; (void)ws_size;
    const float* x_input     = (const float*)d_in[0];
    const int*   indices     = (const int*)d_in[1];
    const float* scores      = (const float*)d_in[2];
    const float* attn_w      = (const float*)d_in[3];
    const float* attn_out_w  = (const float*)d_in[4];
    const float* attn_norm_w = (const float*)d_in[5];
    const float* ffn_norm_w  = (const float*)d_in[6];
    const float* ffn_experts = (const float*)d_in[7];
    const float* keys        = (const float*)d_in[8];
    const float* head_probs  = (const float*)d_in[9];
    const float* score_probs = (const float*)d_in[10];
    float* out = (float*)d_out;

    float* ws = (float*)d_ws;
    const size_t MF = 1024 * 1024;
    // Region map (floats), peak 12M floats = 48 MB:
    // A [0,6M): qkv (gemm1 out); after qkv_prep reused as:
    //    aob [0,1M) bf16 | xfi [1M,3M) | xf [3M,5M) | msbuf [5M,5.25M) |
    //    spbuf [5.25M,...) | woutT [5.5M,6M) bf16
    // B [6M,8M): xnb bf16 (1-3) -> qh bf16 (4-5) -> xfb bf16 (8+)
    // C [8M,10M): wqkvT bf16 (2-3) -> khb bf16 (4+)
    // D [10M,11M): vhb bf16 (4-4.5) -> kgath bf16 (7.5+)
    // E [11M,12M): vhT bf16 (4.5-5)
    float* qkv            = ws;
    unsigned short* aob   = (unsigned short*)ws;
    float* xfi            = ws + 1 * MF;
    float* xf             = ws + 3 * MF;
    float* msbuf          = ws + 5 * MF;
    float* spbuf          = ws + 5 * MF + 300 * 1024;
    unsigned short* woutT = (unsigned short*)(ws + 5 * MF + 512 * 1024);
    unsigned short* xnb   = (unsigned short*)(ws + 6 * MF);
    unsigned short* qh    = (unsigned short*)(ws + 6 * MF);
    unsigned short* xfb   = (unsigned short*)(ws + 6 * MF);
    unsigned short* wqkvT = (unsigned short*)(ws + 8 * MF);
    unsigned short* khb   = (unsigned short*)(ws + 8 * MF);
    unsigned short* vhb   = (unsigned short*)(ws + 10 * MF);
    unsigned short* kgath = (unsigned short*)(ws + 10 * MF);  // after flash
    unsigned short* vhT   = (unsigned short*)(ws + 11 * MF);

    // 1) rmsnorm -> bf16 A
    rmsnorm_bf16_kernel<<<T_, 256, 0, stream>>>(x_input, attn_norm_w, xnb);

    // 2) attn_w (1024 x 3072) -> wqkvT [3072][1024] bf16
    {
        dim3 g(3 * D_ / 32, D_ / 32);
        convt_kernel<<<g, 256, 0, stream>>>(attn_w, wqkvT, D_, 3 * D_);
    }

    // 3) qkv = xnb @ attn_w   (MFMA)
    {
        dim3 g(3 * D_ / 128, T_ / 128);
        mfma_gemm_kernel<0><<<g, 256, 0, stream>>>(xnb, wqkvT, nullptr, qkv,
                                                   T_, 3 * D_, D_);
    }

    // 4) split + l2norm + rope -> bf16 q/k/v
    qkv_prep_kernel<<<T_ * NH_, 64, 0, stream>>>(qkv, qh, khb, vhb);

    // 4.5) transpose V: vhb [h][s][d] -> vhT [h][d][s]
    {
        dim3 g(HD_ / 32, S_ / 32, NH_);
        transpose_v_kernel<<<g, 256, 0, stream>>>(vhb, vhT);
    }

    // 5) MFMA flash attention (barrier-free, 1 q-tile per block) -> aob bf16
    flash_attn_mfma_kernel<<<(S_ / 64) * NH_, 256, 0, stream>>>(qh, khb, vhT, aob);

    // 6) attn_out_w (1024 x 1024) -> woutT [1024][1024] bf16
    {
        dim3 g(D_ / 32, D_ / 32);
        convt_kernel<<<g, 256, 0, stream>>>(attn_out_w, woutT, D_, D_);
    }

    // 7) xfi = aob @ attn_out_w + x_input   (MFMA + residual)
    {
        dim3 g(D_ / 128, T_ / 128);
        mfma_gemm_kernel<1><<<g, 256, 0, stream>>>(aob, woutT, x_input, xfi,
                                                   T_, D_, D_);
    }

    // 7.5) gather keys columns (vhb dead after step 4.5)
    gather_keys_kernel<<<BC_ * ET_ * KH_, 256, 0, stream>>>(keys, indices, kgath);

    // 8) rmsnorm dual: xf fp32 + xfb bf16
    rmsnorm_dual_kernel<<<T_, 256, 0, stream>>>(xfi, ffn_norm_w, xf, xfb);

    // 9a) expert score GEMM per chunk -> msbuf
    score_gemm_kernel<<<BC_, 256, 0, stream>>>(xfb, kgath, msbuf);

    // 9b) gather sp0/sp1/hp -> spbuf
    gather_sp_kernel<<<BC_, 256, 0, stream>>>(score_probs, head_probs,
                                              indices, spbuf);

    // 10) MoE (fused combine weights) + final residual
    moe_kernel<<<T_, 256, 0, stream>>>(xf, xfi, indices, msbuf, scores, spbuf,
                                       ffn_experts, out);
}

// Round 2
// 435.578 us; speedup vs baseline: 1.1127x; 1.1127x over previous
//
#include <hip/hip_runtime.h>
#include <hip/hip_bf16.h>
#include <math.h>

// Problem constants
#define D_   1024
#define HD_  64
#define NH_  16
#define H_   16
#define KH_  8
#define NT_  128      // tokens per chunk (N)
#define E_   4096
#define RE_  4
#define DE_  4
#define ET_  16
#define S_   2048
#define T_   2048
#define BC_  16
#define EPS_ 1e-5f

typedef short s16x8 __attribute__((ext_vector_type(8)));
typedef float f32x4 __attribute__((ext_vector_type(4)));

__device__ __forceinline__ unsigned short f2bf(float f) {
    union { float f; unsigned int u; } v; v.f = f;
    unsigned int r = (v.u + 0x7fffu + ((v.u >> 16) & 1u)) >> 16;  // RNE
    return (unsigned short)r;
}
__device__ __forceinline__ float bf2f(unsigned short u) {
    union { unsigned int i; float f; } v;
    v.i = ((unsigned int)u) << 16;
    return v.f;
}

// ---------------------------------------------------------------------------
// rmsnorm (fp32 out)
// ---------------------------------------------------------------------------
__global__ __launch_bounds__(256) void rmsnorm_kernel(
    const float* __restrict__ x, const float* __restrict__ w,
    float* __restrict__ out)
{
    int row = blockIdx.x, tid = threadIdx.x;
    __shared__ float sred[4];
    float4 v = ((const float4*)(x + (size_t)row * D_))[tid];
    float ss = v.x*v.x + v.y*v.y + v.z*v.z + v.w*v.w;
#pragma unroll
    for (int off = 32; off > 0; off >>= 1) ss += __shfl_xor(ss, off);
    if ((tid & 63) == 0) sred[tid >> 6] = ss;
    __syncthreads();
    float tot = sred[0] + sred[1] + sred[2] + sred[3];
    float scale = rsqrtf(tot * (1.0f / D_) + EPS_);
    float4 wv = ((const float4*)w)[tid];
    float4 o;
    o.x = v.x * scale * wv.x;
    o.y = v.y * scale * wv.y;
    o.z = v.z * scale * wv.z;
    o.w = v.w * scale * wv.w;
    ((float4*)(out + (size_t)row * D_))[tid] = o;
}

// rmsnorm (bf16 out)
__global__ __launch_bounds__(256) void rmsnorm_bf16_kernel(
    const float* __restrict__ x, const float* __restrict__ w,
    unsigned short* __restrict__ out)
{
    int row = blockIdx.x, tid = threadIdx.x;
    __shared__ float sred[4];
    float4 v = ((const float4*)(x + (size_t)row * D_))[tid];
    float ss = v.x*v.x + v.y*v.y + v.z*v.z + v.w*v.w;
#pragma unroll
    for (int off = 32; off > 0; off >>= 1) ss += __shfl_xor(ss, off);
    if ((tid & 63) == 0) sred[tid >> 6] = ss;
    __syncthreads();
    float tot = sred[0] + sred[1] + sred[2] + sred[3];
    float scale = rsqrtf(tot * (1.0f / D_) + EPS_);
    float4 wv = ((const float4*)w)[tid];
    ushort4 o;
    o.x = f2bf(v.x * scale * wv.x);
    o.y = f2bf(v.y * scale * wv.y);
    o.z = f2bf(v.z * scale * wv.z);
    o.w = f2bf(v.w * scale * wv.w);
    *(ushort4*)(out + (size_t)row * D_ + tid * 4) = o;
}

// rmsnorm dual: fp32 out + bf16 out
__global__ __launch_bounds__(256) void rmsnorm_dual_kernel(
    const float* __restrict__ x, const float* __restrict__ w,
    float* __restrict__ out, unsigned short* __restrict__ outb)
{
    int row = blockIdx.x, tid = threadIdx.x;
    __shared__ float sred[4];
    float4 v = ((const float4*)(x + (size_t)row * D_))[tid];
    float ss = v.x*v.x + v.y*v.y + v.z*v.z + v.w*v.w;
#pragma unroll
    for (int off = 32; off > 0; off >>= 1) ss += __shfl_xor(ss, off);
    if ((tid & 63) == 0) sred[tid >> 6] = ss;
    __syncthreads();
    float tot = sred[0] + sred[1] + sred[2] + sred[3];
    float scale = rsqrtf(tot * (1.0f / D_) + EPS_);
    float4 wv = ((const float4*)w)[tid];
    float4 o;
    o.x = v.x * scale * wv.x;
    o.y = v.y * scale * wv.y;
    o.z = v.z * scale * wv.z;
    o.w = v.w * scale * wv.w;
    ((float4*)(out + (size_t)row * D_))[tid] = o;
    ushort4 ob;
    ob.x = f2bf(o.x); ob.y = f2bf(o.y); ob.z = f2bf(o.z); ob.w = f2bf(o.w);
    *(ushort4*)(outb + (size_t)row * D_ + tid * 4) = ob;
}

// ---------------------------------------------------------------------------
// convert + transpose: src [R][Ncols] fp32  ->  dst [Ncols][R] bf16
// ---------------------------------------------------------------------------
__global__ __launch_bounds__(256) void convt_kernel(
    const float* __restrict__ src, unsigned short* __restrict__ dst,
    int R, int Ncols)
{
    __shared__ float tile[32][33];
    int bx = blockIdx.x * 32;   // col block
    int by = blockIdx.y * 32;   // row block
    int tx = threadIdx.x & 31, ty = threadIdx.x >> 5;  // 8 rows per pass
#pragma unroll
    for (int rr = 0; rr < 32; rr += 8)
        tile[ty + rr][tx] = src[(size_t)(by + ty + rr) * Ncols + bx + tx];
    __syncthreads();
#pragma unroll
    for (int rr = 0; rr < 32; rr += 8)
        dst[(size_t)(bx + ty + rr) * R + by + tx] = f2bf(tile[tx][ty + rr]);
}

// ---------------------------------------------------------------------------
// bf16 transpose: vhb [NH][S][HD] -> vhT [NH][HD][S]
// ---------------------------------------------------------------------------
__global__ __launch_bounds__(256) void transpose_v_kernel(
    const unsigned short* __restrict__ src, unsigned short* __restrict__ dst)
{
    __shared__ unsigned short tile[32][34];
    int h  = blockIdx.z;
    int d0 = blockIdx.x * 32;   // HD/32 = 2
    int s0 = blockIdx.y * 32;   // S/32 = 64
    int tx = threadIdx.x & 31, ty = threadIdx.x >> 5;
    const unsigned short* sp = src + ((size_t)h * S_ + s0) * HD_ + d0;
#pragma unroll
    for (int rr = 0; rr < 32; rr += 8)
        tile[ty + rr][tx] = sp[(size_t)(ty + rr) * HD_ + tx];
    __syncthreads();
    unsigned short* dp = dst + ((size_t)h * HD_ + d0) * S_ + s0;
#pragma unroll
    for (int rr = 0; rr < 32; rr += 8)
        dp[(size_t)(ty + rr) * S_ + tx] = tile[tx][ty + rr];
}

// ---------------------------------------------------------------------------
// MFMA GEMM: C[M,N] fp32 = A[M,K] bf16 @ Bt[N,K] bf16 (+ res fp32)
// ---------------------------------------------------------------------------
template <int WITH_RES>
__global__ __launch_bounds__(256) void mfma_gemm_kernel(
    const unsigned short* __restrict__ A, const unsigned short* __restrict__ Bt,
    const float* __restrict__ res, float* __restrict__ C,
    int M, int N, int K)
{
    __shared__ short As[128][40];
    __shared__ short Bs[128][40];
    int tid = threadIdx.x;
    int wave = tid >> 6, lane = tid & 63;
    int ml = lane & 15, q = lane >> 4;
    int wr = wave >> 1, wc = wave & 1;
    int bm = blockIdx.y * 128, bn = blockIdx.x * 128;
    int srow = tid >> 2;
    int scol = (tid & 3) * 8;

    f32x4 acc[4][4];
#pragma unroll
    for (int i = 0; i < 4; i++)
#pragma unroll
        for (int j = 0; j < 4; j++) acc[i][j] = (f32x4){0.f, 0.f, 0.f, 0.f};

    for (int k0 = 0; k0 < K; k0 += 32) {
        int4 a0 = *(const int4*)(A + (size_t)(bm + srow) * K + k0 + scol);
        int4 a1 = *(const int4*)(A + (size_t)(bm + srow + 64) * K + k0 + scol);
        int4 b0 = *(const int4*)(Bt + (size_t)(bn + srow) * K + k0 + scol);
        int4 b1 = *(const int4*)(Bt + (size_t)(bn + srow + 64) * K + k0 + scol);
        __syncthreads();
        *(int4*)(&As[srow][scol]) = a0;
        *(int4*)(&As[srow + 64][scol]) = a1;
        *(int4*)(&Bs[srow][scol]) = b0;
        *(int4*)(&Bs[srow + 64][scol]) = b1;
        __syncthreads();

        s16x8 af[4], bf[4];
#pragma unroll
        for (int i = 0; i < 4; i++)
            af[i] = *(const s16x8*)(&As[wr * 64 + i * 16 + ml][q * 8]);
#pragma unroll
        for (int j = 0; j < 4; j++)
            bf[j] = *(const s16x8*)(&Bs[wc * 64 + j * 16 + ml][q * 8]);
#pragma unroll
        for (int i = 0; i < 4; i++)
#pragma unroll
            for (int j = 0; j < 4; j++)
                acc[i][j] = __builtin_amdgcn_mfma_f32_16x16x32_bf16(
                    af[i], bf[j], acc[i][j], 0, 0, 0);
    }

#pragma unroll
    for (int i = 0; i < 4; i++) {
#pragma unroll
        for (int j = 0; j < 4; j++) {
            int col = bn + wc * 64 + j * 16 + ml;
#pragma unroll
            for (int r = 0; r < 4; r++) {
                int row = bm + wr * 64 + i * 16 + q * 4 + r;
                float v = acc[i][j][r];
                if (WITH_RES) v += res[(size_t)row * N + col];
                C[(size_t)row * N + col] = v;
            }
        }
    }
}

// ---------------------------------------------------------------------------
// qkv prep: split qkv into per-head (NH,S,HD) bf16 q/k/v with l2norm + rope.
// ---------------------------------------------------------------------------
__global__ __launch_bounds__(64) void qkv_prep_kernel(
    const float* __restrict__ qkv, unsigned short* __restrict__ qh,
    unsigned short* __restrict__ khb, unsigned short* __restrict__ vhb)
{
    int bid = blockIdx.x;
    int s = bid / NH_, h = bid % NH_;
    int lane = threadIdx.x;

    size_t qoff = (size_t)s * (3 * D_) + h * HD_ + lane;
    float qv = qkv[qoff];
    float kv = qkv[qoff + D_];
    float vv = qkv[qoff + 2 * D_];

    float sq = qv * qv, sk = kv * kv;
#pragma unroll
    for (int off = 32; off > 0; off >>= 1) {
        sq += __shfl_xor(sq, off);
        sk += __shfl_xor(sk, off);
    }
    qv /= fmaxf(sqrtf(sq), EPS_);
    kv /= fmaxf(sqrtf(sk), EPS_);

    int j = lane & 31;
    float sign = (lane < 32) ? 1.0f : -1.0f;
    float inv_freq = exp2f((float)j * (-13.287712379549449f / 32.0f));
    float f = (float)s * inv_freq;
    float sn, cs;
    sincosf(f, &sn, &cs);
    float qo = __shfl_xor(qv, 32);
    float ko = __shfl_xor(kv, 32);
    qv = qv * cs + sign * qo * sn;
    kv = kv * cs + sign * ko * sn;

    size_t o = ((size_t)h * S_ + s) * HD_ + lane;
    qh[o]  = f2bf(qv * 0.125f);   // fold 1/sqrt(64)
    khb[o] = f2bf(kv);
    vhb[o] = f2bf(vv);
}

// ---------------------------------------------------------------------------
// MFMA bf16 flash attention, double-buffered LDS + async reg staging.
//   512 blocks, one 64-row q-tile each. Dispatch remap interleaves heavy and
//   light tiles: bids [0,256) get t=0..15, bids [256,512) get t=31..16, so a
//   round-robin CU assignment pairs t with 31-t (33 k-iters per CU).
//   K and pre-transposed V staged through double-buffered LDS; next tile's
//   global loads are issued BEFORE the current tile's compute (T14), so L2/
//   HBM latency hides under MFMA+softmax. P exchange is per-wave (no sync).
// ---------------------------------------------------------------------------
#define FS 72   // shorts per LDS row (pad: 144B rows -> 2-way banks, free)
__global__ __launch_bounds__(256) void flash_attn_mfma_kernel(
    const unsigned short* __restrict__ qh, const unsigned short* __restrict__ khb,
    const unsigned short* __restrict__ vhT, unsigned short* __restrict__ aob)
{
    __shared__ __align__(16) short Ks[2][64][FS];
    __shared__ __align__(16) short Vs[2][64][FS];   // [buf][d][token]
    __shared__ __align__(16) short Ps[4][16][FS];   // per-wave scratch
    int u = blockIdx.x & 255;
    int v = blockIdx.x >> 8;
    int h = u & 15;
    int p = u >> 4;
    int t = v ? (31 - p) : p;
    int tid = threadIdx.x;
    int wq = tid >> 6;
    int lane = tid & 63;
    int ml = lane & 15, quad = lane >> 4;
    int srow = tid >> 2;          // 0..63
    int sc = (tid & 3) * 16;      // 0,16,32,48 (shorts)
    const unsigned short* Qb = qh  + (size_t)h * S_ * HD_;
    const unsigned short* Kb = khb + (size_t)h * S_ * HD_;
    const unsigned short* Vt = vhT + (size_t)h * HD_ * S_;

    int q0 = t * 64;
    int qrow = q0 + wq * 16 + ml;
    s16x8 aq0 = *(const s16x8*)(Qb + (size_t)qrow * HD_ + quad * 8);
    s16x8 aq1 = *(const s16x8*)(Qb + (size_t)qrow * HD_ + 32 + quad * 8);

    float m[4], l[4];
    f32x4 o[4];
#pragma unroll
    for (int r = 0; r < 4; r++) { m[r] = -INFINITY; l[r] = 0.f; }
#pragma unroll
    for (int nb = 0; nb < 4; nb++) o[nb] = (f32x4){0.f, 0.f, 0.f, 0.f};

    int4 kr0, kr1, vr0, vr1;      // staging registers
    // prologue: tile 0 -> buf 0
    {
        const unsigned short* kp = Kb + (size_t)srow * HD_ + sc;
        kr0 = *(const int4*)kp; kr1 = *(const int4*)(kp + 8);
        const unsigned short* vp = Vt + (size_t)srow * S_ + sc;
        vr0 = *(const int4*)vp; vr1 = *(const int4*)(vp + 8);
        *(int4*)(&Ks[0][srow][sc]) = kr0; *(int4*)(&Ks[0][srow][sc + 8]) = kr1;
        *(int4*)(&Vs[0][srow][sc]) = vr0; *(int4*)(&Vs[0][srow][sc + 8]) = vr1;
    }
    __syncthreads();
    int cur = 0;

    for (int kt = 0; kt <= t; kt++) {
        int k0 = kt * 64;
        // issue next tile's global loads early (latency hides under compute)
        if (kt < t) {
            const unsigned short* kp = Kb + (size_t)(k0 + 64 + srow) * HD_ + sc;
            kr0 = *(const int4*)kp; kr1 = *(const int4*)(kp + 8);
            const unsigned short* vp = Vt + (size_t)srow * S_ + k0 + 64 + sc;
            vr0 = *(const int4*)vp; vr1 = *(const int4*)(vp + 8);
        }

        f32x4 s[4];
#pragma unroll
        for (int nb = 0; nb < 4; nb++) s[nb] = (f32x4){0.f, 0.f, 0.f, 0.f};
        __builtin_amdgcn_s_setprio(1);
#pragma unroll
        for (int nb = 0; nb < 4; nb++) {
            s16x8 b0 = *(const s16x8*)(&Ks[cur][nb * 16 + ml][quad * 8]);
            s16x8 b1 = *(const s16x8*)(&Ks[cur][nb * 16 + ml][32 + quad * 8]);
            s[nb] = __builtin_amdgcn_mfma_f32_16x16x32_bf16(aq0, b0, s[nb], 0, 0, 0);
            s[nb] = __builtin_amdgcn_mfma_f32_16x16x32_bf16(aq1, b1, s[nb], 0, 0, 0);
        }
        __builtin_amdgcn_s_setprio(0);

        float sv[4][4];
#pragma unroll
        for (int nb = 0; nb < 4; nb++)
#pragma unroll
            for (int r = 0; r < 4; r++) {
                float val = s[nb][r];
                if (kt == t && (nb * 16 + ml) > (wq * 16 + quad * 4 + r))
                    val = -1e30f;
                sv[nb][r] = val;
            }
#pragma unroll
        for (int r = 0; r < 4; r++) {
            float rm = fmaxf(fmaxf(sv[0][r], sv[1][r]),
                             fmaxf(sv[2][r], sv[3][r]));
#pragma unroll
            for (int off = 1; off < 16; off <<= 1)
                rm = fmaxf(rm, __shfl_xor(rm, off));
            float mn = fmaxf(m[r], rm);
            float corr = __expf(m[r] - mn);
            m[r] = mn;
            float rs = 0.f;
#pragma unroll
            for (int nb = 0; nb < 4; nb++) {
                float pe = __expf(sv[nb][r] - mn);
                sv[nb][r] = pe;
                rs += pe;
            }
#pragma unroll
            for (int off = 1; off < 16; off <<= 1)
                rs += __shfl_xor(rs, off);
            l[r] = l[r] * corr + rs;
#pragma unroll
            for (int nb = 0; nb < 4; nb++) o[nb][r] *= corr;
        }

        // intra-wave P exchange (no barriers: per-wave LDS slice, in-order)
#pragma unroll
        for (int nb = 0; nb < 4; nb++)
#pragma unroll
            for (int r = 0; r < 4; r++)
                Ps[wq][quad * 4 + r][nb * 16 + ml] = (short)f2bf(sv[nb][r]);

        s16x8 ap0 = *(const s16x8*)(&Ps[wq][ml][quad * 8]);
        s16x8 ap1 = *(const s16x8*)(&Ps[wq][ml][32 + quad * 8]);
        __builtin_amdgcn_s_setprio(1);
#pragma unroll
        for (int nb = 0; nb < 4; nb++) {
            s16x8 b0 = *(const s16x8*)(&Vs[cur][nb * 16 + ml][quad * 8]);
            s16x8 b1 = *(const s16x8*)(&Vs[cur][nb * 16 + ml][32 + quad * 8]);
            o[nb] = __builtin_amdgcn_mfma_f32_16x16x32_bf16(ap0, b0, o[nb], 0, 0, 0);
            o[nb] = __builtin_amdgcn_mfma_f32_16x16x32_bf16(ap1, b1, o[nb], 0, 0, 0);
        }
        __builtin_amdgcn_s_setprio(0);

        __syncthreads();                       // B1: reads of buf[cur] done
        if (kt < t) {
            *(int4*)(&Ks[cur ^ 1][srow][sc])     = kr0;
            *(int4*)(&Ks[cur ^ 1][srow][sc + 8]) = kr1;
            *(int4*)(&Vs[cur ^ 1][srow][sc])     = vr0;
            *(int4*)(&Vs[cur ^ 1][srow][sc + 8]) = vr1;
            __syncthreads();                   // B2: buf[cur^1] visible
            cur ^= 1;
        }
    }

#pragma unroll
    for (int r = 0; r < 4; r++) {
        float inv = 1.0f / l[r];
        int row = q0 + wq * 16 + quad * 4 + r;
#pragma unroll
        for (int nb = 0; nb < 4; nb++)
            aob[(size_t)row * D_ + h * HD_ + nb * 16 + ml] =
                f2bf(o[nb][r] * inv);
    }
}

// ---------------------------------------------------------------------------
// gather keys columns into compact bf16 buffer.
// block (pair, kh) -> kgath[pair][kh][0..1024) bf16
// Per chunk c, row n = e*8+kh at offset (c*128+n)*1024: contiguous Bt layout.
// ---------------------------------------------------------------------------
__global__ __launch_bounds__(256) void gather_keys_kernel(
    const float* __restrict__ keys, const int* __restrict__ indices,
    unsigned short* __restrict__ kgath)
{
    int bid = blockIdx.x;
    int pair = bid >> 3, kh = bid & 7;
    int idx = indices[pair];
    int tid = threadIdx.x;
    const float* kp = keys + (size_t)kh * D_ * E_ + idx;
    int d = tid * 4;
    ushort4 o;
    o.x = f2bf(kp[(size_t)(d + 0) * E_]);
    o.y = f2bf(kp[(size_t)(d + 1) * E_]);
    o.z = f2bf(kp[(size_t)(d + 2) * E_]);
    o.w = f2bf(kp[(size_t)(d + 3) * E_]);
    *(ushort4*)(kgath + ((size_t)pair * KH_ + kh) * D_ + d) = o;
}

// ---------------------------------------------------------------------------
// expert score GEMM (one block per chunk): msbuf[c][128 t][128 n] fp32 =
//   xfb[c*128..][1024] @ kgath[c*128..][1024]^T   (n = e*8+kh)
// ---------------------------------------------------------------------------
__global__ __launch_bounds__(256) void score_gemm_kernel(
    const unsigned short* __restrict__ xfb, const unsigned short* __restrict__ kgath,
    float* __restrict__ msbuf)
{
    __shared__ short As[128][40];
    __shared__ short Bs[128][40];
    int c = blockIdx.x;
    const unsigned short* A  = xfb   + (size_t)c * 128 * D_;
    const unsigned short* Bt = kgath + (size_t)c * 128 * D_;
    int tid = threadIdx.x;
    int wave = tid >> 6, lane = tid & 63;
    int ml = lane & 15, q = lane >> 4;
    int wr = wave >> 1, wc = wave & 1;
    int srow = tid >> 2;
    int scol = (tid & 3) * 8;

    f32x4 acc[4][4];
#pragma unroll
    for (int i = 0; i < 4; i++)
#pragma unroll
        for (int j = 0; j < 4; j++) acc[i][j] = (f32x4){0.f, 0.f, 0.f, 0.f};

    for (int k0 = 0; k0 < D_; k0 += 32) {
        int4 a0 = *(const int4*)(A + (size_t)srow * D_ + k0 + scol);
        int4 a1 = *(const int4*)(A + (size_t)(srow + 64) * D_ + k0 + scol);
        int4 b0 = *(const int4*)(Bt + (size_t)srow * D_ + k0 + scol);
        int4 b1 = *(const int4*)(Bt + (size_t)(srow + 64) * D_ + k0 + scol);
        __syncthreads();
        *(int4*)(&As[srow][scol]) = a0;
        *(int4*)(&As[srow + 64][scol]) = a1;
        *(int4*)(&Bs[srow][scol]) = b0;
        *(int4*)(&Bs[srow + 64][scol]) = b1;
        __syncthreads();

        s16x8 af[4], bf[4];
#pragma unroll
        for (int i = 0; i < 4; i++)
            af[i] = *(const s16x8*)(&As[wr * 64 + i * 16 + ml][q * 8]);
#pragma unroll
        for (int j = 0; j < 4; j++)
            bf[j] = *(const s16x8*)(&Bs[wc * 64 + j * 16 + ml][q * 8]);
#pragma unroll
        for (int i = 0; i < 4; i++)
#pragma unroll
            for (int j = 0; j < 4; j++)
                acc[i][j] = __builtin_amdgcn_mfma_f32_16x16x32_bf16(
                    af[i], bf[j], acc[i][j], 0, 0, 0);
    }

    float* out = msbuf + (size_t)c * 128 * 128;
#pragma unroll
    for (int i = 0; i < 4; i++)
#pragma unroll
        for (int j = 0; j < 4; j++) {
            int col = wc * 64 + j * 16 + ml;
#pragma unroll
            for (int r = 0; r < 4; r++) {
                int row = wr * 64 + i * 16 + q * 4 + r;
                out[(size_t)row * 128 + col] = acc[i][j][r];
            }
        }
}

// ---------------------------------------------------------------------------
// gather sp0/sp1/hp per (chunk, e, h) into coalesced spbuf[c][3][256]
// ---------------------------------------------------------------------------
__global__ __launch_bounds__(256) void gather_sp_kernel(
    const float* __restrict__ score_probs, const float* __restrict__ head_probs,
    const int* __restrict__ indices, float* __restrict__ spbuf)
{
    int c = blockIdx.x, tid = threadIdx.x;
    int e = tid >> 4, h = tid & 15;
    int idx = indices[c * ET_ + e];
    int r = e >> 2;   // e / DE_
    float v0 = score_probs[((size_t)(0 * RE_ + r) * E_ + idx) * H_ + h];
    float v1 = score_probs[((size_t)(1 * RE_ + r) * E_ + idx) * H_ + h];
    float v2 = head_probs[((size_t)r * E_ + idx) * H_ + h];
    float* sp = spbuf + (size_t)c * 3 * 256;
    sp[tid] = v0;
    sp[256 + tid] = v1;
    sp[512 + tid] = v2;
}

// ---------------------------------------------------------------------------
// MoE with rank-1 experts + fused combine-weight computation.
// One block per token; prologue computes sw[e] from msbuf/scores/spbuf.
// ---------------------------------------------------------------------------
__global__ __launch_bounds__(256) void moe_kernel(
    const float* __restrict__ xf, const float* __restrict__ xfi,
    const int* __restrict__ indices, const float* __restrict__ msbuf,
    const float* __restrict__ scores, const float* __restrict__ spbuf,
    const float* __restrict__ experts, float* __restrict__ out)
{
    int t = blockIdx.x, tid = threadIdx.x;
    int c = t / NT_;
    __shared__ int sidx[ET_];
    __shared__ float sw[ET_];
    __shared__ float r0[4], r1[4];
    if (tid < ET_) sidx[tid] = indices[c * ET_ + tid];
    // ---- combine weights: thread = (e = tid>>4, h = tid&15) ----
    {
        int e = tid >> 4, h = tid & 15;
        float ms = msbuf[(size_t)t * 128 + e * 8 + (h >> 1)];
        float sc = scores[(size_t)t * (ET_ * H_) + tid];
        const float* sp = spbuf + (size_t)c * 3 * 256;
        float z = sp[tid] * ms + sp[256 + tid] * sc;
        float term = sp[512 + tid] / (1.0f + __expf(-z));
#pragma unroll
        for (int off = 1; off < 16; off <<= 1)
            term += __shfl_xor(term, off);
        if (h == 0) sw[e] = term;
    }
    float4 xv = ((const float4*)(xf + (size_t)t * D_))[tid];
    float acc[4] = {0.f, 0.f, 0.f, 0.f};
    __syncthreads();
    for (int e = 0; e < ET_; e++) {
        int idx = sidx[e];
        size_t base = (size_t)idx * D_;
        float4 w0 = *(const float4*)(experts + base + tid * 4);
        float4 w1 = *(const float4*)(experts + (size_t)E_ * D_ + base + tid * 4);
        float p0 = xv.x * w0.x + xv.y * w0.y + xv.z * w0.z + xv.w * w0.w;
        float p1 = xv.x * w1.x + xv.y * w1.y + xv.z * w1.z + xv.w * w1.w;
#pragma unroll
        for (int off = 32; off > 0; off >>= 1) {
            p0 += __shfl_xor(p0, off);
            p1 += __shfl_xor(p1, off);
        }
        if ((tid & 63) == 0) { r0[tid >> 6] = p0; r1[tid >> 6] = p1; }
        __syncthreads();
        float h0 = r0[0] + r0[1] + r0[2] + r0[3];
        float h1 = r1[0] + r1[1] + r1[2] + r1[3];
        __syncthreads();
        float act = h0 / (1.0f + __expf(-h0)) * h1 * sw[e];
        float4 w2 = *(const float4*)(experts + (size_t)2 * E_ * D_ + base + tid * 4);
        acc[0] += act * w2.x;
        acc[1] += act * w2.y;
        acc[2] += act * w2.z;
        acc[3] += act * w2.w;
    }
    size_t o = (size_t)t * D_ + tid * 4;
    float4 rv = *(const float4*)(xfi + o);
    float4 ov;
    ov.x = acc[0] + rv.x;
    ov.y = acc[1] + rv.y;
    ov.z = acc[2] + rv.z;
    ov.w = acc[3] + rv.w;
    *(float4*)(out + o) = ov;
}

// ---------------------------------------------------------------------------
extern "C" void kernel_launch(void* const* d_in, const int* in_sizes, int n_in,
                              void* d_out, int out_size, void* d_ws, size_t ws_size,
                              hipStream_t stream)
{
    (void)in_sizes; (void)n_in; (void)out_size; (void)ws_size;
    const float* x_input     = (const float*)d_in[0];
    const int*   indices     = (const int*)d_in[1];
    const float* scores      = (const float*)d_in[2];
    const float* attn_w      = (const float*)d_in[3];
    const float* attn_out_w  = (const float*)d_in[4];
    const float* attn_norm_w = (const float*)d_in[5];
    const float* ffn_norm_w  = (const float*)d_in[6];
    const float* ffn_experts = (const float*)d_in[7];
    const float* keys        = (const float*)d_in[8];
    const float* head_probs  = (const float*)d_in[9];
    const float* score_probs = (const float*)d_in[10];
    float* out = (float*)d_out;

    float* ws = (float*)d_ws;
    const size_t MF = 1024 * 1024;
    // Region map (floats), peak 12M floats = 48 MB:
    // A [0,6M): qkv (gemm1 out); after qkv_prep reused as:
    //    aob [0,1M) bf16 | xfi [1M,3M) | xf [3M,5M) | msbuf [5M,5.25M) |
    //    spbuf [5.25M,...) | woutT [5.5M,6M) bf16
    // B [6M,8M): xnb bf16 (1-3) -> qh bf16 (4-5) -> xfb bf16 (8+)
    // C [8M,10M): wqkvT bf16 (2-3) -> khb bf16 (4+)
    // D [10M,11M): vhb bf16 (4-4.5) -> kgath bf16 (7.5+)
    // E [11M,12M): vhT bf16 (4.5-5)
    float* qkv            = ws;
    unsigned short* aob   = (unsigned short*)ws;
    float* xfi            = ws + 1 * MF;
    float* xf             = ws + 3 * MF;
    float* msbuf          = ws + 5 * MF;
    float* spbuf          = ws + 5 * MF + 300 * 1024;
    unsigned short* woutT = (unsigned short*)(ws + 5 * MF + 512 * 1024);
    unsigned short* xnb   = (unsigned short*)(ws + 6 * MF);
    unsigned short* qh    = (unsigned short*)(ws + 6 * MF);
    unsigned short* xfb   = (unsigned short*)(ws + 6 * MF);
    unsigned short* wqkvT = (unsigned short*)(ws + 8 * MF);
    unsigned short* khb   = (unsigned short*)(ws + 8 * MF);
    unsigned short* vhb   = (unsigned short*)(ws + 10 * MF);
    unsigned short* kgath = (unsigned short*)(ws + 10 * MF);  // after flash
    unsigned short* vhT   = (unsigned short*)(ws + 11 * MF);

    // 1) rmsnorm -> bf16 A
    rmsnorm_bf16_kernel<<<T_, 256, 0, stream>>>(x_input, attn_norm_w, xnb);

    // 2) attn_w (1024 x 3072) -> wqkvT [3072][1024] bf16
    {
        dim3 g(3 * D_ / 32, D_ / 32);
        convt_kernel<<<g, 256, 0, stream>>>(attn_w, wqkvT, D_, 3 * D_);
    }

    // 3) qkv = xnb @ attn_w   (MFMA)
    {
        dim3 g(3 * D_ / 128, T_ / 128);
        mfma_gemm_kernel<0><<<g, 256, 0, stream>>>(xnb, wqkvT, nullptr, qkv,
                                                   T_, 3 * D_, D_);
    }

    // 4) split + l2norm + rope -> bf16 q/k/v
    qkv_prep_kernel<<<T_ * NH_, 64, 0, stream>>>(qkv, qh, khb, vhb);

    // 4.5) transpose V: vhb [h][s][d] -> vhT [h][d][s]
    {
        dim3 g(HD_ / 32, S_ / 32, NH_);
        transpose_v_kernel<<<g, 256, 0, stream>>>(vhb, vhT);
    }

    // 5) MFMA flash attention (dbuf LDS, balanced 512-block grid) -> aob bf16
    flash_attn_mfma_kernel<<<(S_ / 64) * NH_, 256, 0, stream>>>(qh, khb, vhT, aob);

    // 6) attn_out_w (1024 x 1024) -> woutT [1024][1024] bf16
    {
        dim3 g(D_ / 32, D_ / 32);
        convt_kernel<<<g, 256, 0, stream>>>(attn_out_w, woutT, D_, D_);
    }

    // 7) xfi = aob @ attn_out_w + x_input   (MFMA + residual)
    {
        dim3 g(D_ / 128, T_ / 128);
        mfma_gemm_kernel<1><<<g, 256, 0, stream>>>(aob, woutT, x_input, xfi,
                                                   T_, D_, D_);
    }

    // 7.5) gather keys columns (vhb dead after step 4.5)
    gather_keys_kernel<<<BC_ * ET_ * KH_, 256, 0, stream>>>(keys, indices, kgath);

    // 8) rmsnorm dual: xf fp32 + xfb bf16
    rmsnorm_dual_kernel<<<T_, 256, 0, stream>>>(xfi, ffn_norm_w, xf, xfb);

    // 9a) expert score GEMM per chunk -> msbuf
    score_gemm_kernel<<<BC_, 256, 0, stream>>>(xfb, kgath, msbuf);

    // 9b) gather sp0/sp1/hp -> spbuf
    gather_sp_kernel<<<BC_, 256, 0, stream>>>(score_probs, head_probs,
                                              indices, spbuf);

    // 10) MoE (fused combine weights) + final residual
    moe_kernel<<<T_, 256, 0, stream>>>(xf, xfi, indices, msbuf, scores, spbuf,
                                       ffn_experts, out);
}

// Round 3
// 410.623 us; speedup vs baseline: 1.1803x; 1.0608x over previous
//
#include <hip/hip_runtime.h>
#include <hip/hip_bf16.h>
#include <math.h>

// Problem constants
#define D_   1024
#define HD_  64
#define NH_  16
#define H_   16
#define KH_  8
#define NT_  128      // tokens per chunk (N)
#define E_   4096
#define RE_  4
#define DE_  4
#define ET_  16
#define S_   2048
#define T_   2048
#define BC_  16
#define EPS_ 1e-5f

typedef short s16x8 __attribute__((ext_vector_type(8)));
typedef float f32x4 __attribute__((ext_vector_type(4)));

__device__ __forceinline__ unsigned short f2bf(float f) {
    union { float f; unsigned int u; } v; v.f = f;
    unsigned int r = (v.u + 0x7fffu + ((v.u >> 16) & 1u)) >> 16;  // RNE
    return (unsigned short)r;
}
__device__ __forceinline__ float bf2f(unsigned short u) {
    union { unsigned int i; float f; } v;
    v.i = ((unsigned int)u) << 16;
    return v.f;
}

// async global->LDS, 16B per lane; LDS dest is wave-uniform base + lane*16.
#define GLOAD16(gp, lp) __builtin_amdgcn_global_load_lds(                      \
    (__attribute__((address_space(1))) void*)(gp),                             \
    (__attribute__((address_space(3))) void*)(lp), 16, 0, 0)

// ---------------------------------------------------------------------------
// rmsnorm (bf16 out)
// ---------------------------------------------------------------------------
__global__ __launch_bounds__(256) void rmsnorm_bf16_kernel(
    const float* __restrict__ x, const float* __restrict__ w,
    unsigned short* __restrict__ out)
{
    int row = blockIdx.x, tid = threadIdx.x;
    __shared__ float sred[4];
    float4 v = ((const float4*)(x + (size_t)row * D_))[tid];
    float ss = v.x*v.x + v.y*v.y + v.z*v.z + v.w*v.w;
#pragma unroll
    for (int off = 32; off > 0; off >>= 1) ss += __shfl_xor(ss, off);
    if ((tid & 63) == 0) sred[tid >> 6] = ss;
    __syncthreads();
    float tot = sred[0] + sred[1] + sred[2] + sred[3];
    float scale = rsqrtf(tot * (1.0f / D_) + EPS_);
    float4 wv = ((const float4*)w)[tid];
    ushort4 o;
    o.x = f2bf(v.x * scale * wv.x);
    o.y = f2bf(v.y * scale * wv.y);
    o.z = f2bf(v.z * scale * wv.z);
    o.w = f2bf(v.w * scale * wv.w);
    *(ushort4*)(out + (size_t)row * D_ + tid * 4) = o;
}

// rmsnorm dual: fp32 out + bf16 out
__global__ __launch_bounds__(256) void rmsnorm_dual_kernel(
    const float* __restrict__ x, const float* __restrict__ w,
    float* __restrict__ out, unsigned short* __restrict__ outb)
{
    int row = blockIdx.x, tid = threadIdx.x;
    __shared__ float sred[4];
    float4 v = ((const float4*)(x + (size_t)row * D_))[tid];
    float ss = v.x*v.x + v.y*v.y + v.z*v.z + v.w*v.w;
#pragma unroll
    for (int off = 32; off > 0; off >>= 1) ss += __shfl_xor(ss, off);
    if ((tid & 63) == 0) sred[tid >> 6] = ss;
    __syncthreads();
    float tot = sred[0] + sred[1] + sred[2] + sred[3];
    float scale = rsqrtf(tot * (1.0f / D_) + EPS_);
    float4 wv = ((const float4*)w)[tid];
    float4 o;
    o.x = v.x * scale * wv.x;
    o.y = v.y * scale * wv.y;
    o.z = v.z * scale * wv.z;
    o.w = v.w * scale * wv.w;
    ((float4*)(out + (size_t)row * D_))[tid] = o;
    ushort4 ob;
    ob.x = f2bf(o.x); ob.y = f2bf(o.y); ob.z = f2bf(o.z); ob.w = f2bf(o.w);
    *(ushort4*)(outb + (size_t)row * D_ + tid * 4) = ob;
}

// ---------------------------------------------------------------------------
// convert + transpose: src [R][Ncols] fp32  ->  dst [Ncols][R] bf16
// ---------------------------------------------------------------------------
__global__ __launch_bounds__(256) void convt_kernel(
    const float* __restrict__ src, unsigned short* __restrict__ dst,
    int R, int Ncols)
{
    __shared__ float tile[32][33];
    int bx = blockIdx.x * 32;   // col block
    int by = blockIdx.y * 32;   // row block
    int tx = threadIdx.x & 31, ty = threadIdx.x >> 5;  // 8 rows per pass
#pragma unroll
    for (int rr = 0; rr < 32; rr += 8)
        tile[ty + rr][tx] = src[(size_t)(by + ty + rr) * Ncols + bx + tx];
    __syncthreads();
#pragma unroll
    for (int rr = 0; rr < 32; rr += 8)
        dst[(size_t)(bx + ty + rr) * R + by + tx] = f2bf(tile[tx][ty + rr]);
}

// ---------------------------------------------------------------------------
// bf16 transpose: vhb [NH][S][HD] -> vhT [NH][HD][S]
// ---------------------------------------------------------------------------
__global__ __launch_bounds__(256) void transpose_v_kernel(
    const unsigned short* __restrict__ src, unsigned short* __restrict__ dst)
{
    __shared__ unsigned short tile[32][34];
    int h  = blockIdx.z;
    int d0 = blockIdx.x * 32;   // HD/32 = 2
    int s0 = blockIdx.y * 32;   // S/32 = 64
    int tx = threadIdx.x & 31, ty = threadIdx.x >> 5;
    const unsigned short* sp = src + ((size_t)h * S_ + s0) * HD_ + d0;
#pragma unroll
    for (int rr = 0; rr < 32; rr += 8)
        tile[ty + rr][tx] = sp[(size_t)(ty + rr) * HD_ + tx];
    __syncthreads();
    unsigned short* dp = dst + ((size_t)h * HD_ + d0) * S_ + s0;
#pragma unroll
    for (int rr = 0; rr < 32; rr += 8)
        dp[(size_t)(ty + rr) * S_ + tx] = tile[tx][ty + rr];
}

// ---------------------------------------------------------------------------
// MFMA GEMM: C[M,N] fp32 = A[M,K] bf16 @ Bt[N,K] bf16 (+ res fp32)
// m97 structure: global_load_lds width-16 staging into linear LDS [128][32].
// ---------------------------------------------------------------------------
template <int WITH_RES>
__global__ __launch_bounds__(256) void mfma_gemm_kernel(
    const unsigned short* __restrict__ A, const unsigned short* __restrict__ Bt,
    const float* __restrict__ res, float* __restrict__ C,
    int M, int N, int K)
{
    __shared__ __align__(16) short As[128][32];
    __shared__ __align__(16) short Bs[128][32];
    int tid = threadIdx.x;
    int wave = tid >> 6, lane = tid & 63;
    int ml = lane & 15, q = lane >> 4;
    int wr = wave >> 1, wc = wave & 1;
    int bm = blockIdx.y * 128, bn = blockIdx.x * 128;
    int srow = tid >> 2;           // 0..63
    int scol = (tid & 3) * 8;      // shorts

    f32x4 acc[4][4];
#pragma unroll
    for (int i = 0; i < 4; i++)
#pragma unroll
        for (int j = 0; j < 4; j++) acc[i][j] = (f32x4){0.f, 0.f, 0.f, 0.f};

    const unsigned short* Ap = A  + (size_t)(bm + srow) * K + scol;
    const unsigned short* Bp = Bt + (size_t)(bn + srow) * K + scol;
    // wave-uniform LDS bases (each wave's 64 lanes cover 1024B = 16 rows)
    short* ldsA0 = &As[wave * 16][0];
    short* ldsA1 = &As[64 + wave * 16][0];
    short* ldsB0 = &Bs[wave * 16][0];
    short* ldsB1 = &Bs[64 + wave * 16][0];

    for (int k0 = 0; k0 < K; k0 += 32) {
        __syncthreads();
        GLOAD16(Ap + k0, ldsA0);
        GLOAD16(Ap + (size_t)64 * K + k0, ldsA1);
        GLOAD16(Bp + k0, ldsB0);
        GLOAD16(Bp + (size_t)64 * K + k0, ldsB1);
        __syncthreads();

        s16x8 af[4], bf[4];
#pragma unroll
        for (int i = 0; i < 4; i++)
            af[i] = *(const s16x8*)(&As[wr * 64 + i * 16 + ml][q * 8]);
#pragma unroll
        for (int j = 0; j < 4; j++)
            bf[j] = *(const s16x8*)(&Bs[wc * 64 + j * 16 + ml][q * 8]);
#pragma unroll
        for (int i = 0; i < 4; i++)
#pragma unroll
            for (int j = 0; j < 4; j++)
                acc[i][j] = __builtin_amdgcn_mfma_f32_16x16x32_bf16(
                    af[i], bf[j], acc[i][j], 0, 0, 0);
    }

#pragma unroll
    for (int i = 0; i < 4; i++) {
#pragma unroll
        for (int j = 0; j < 4; j++) {
            int col = bn + wc * 64 + j * 16 + ml;
#pragma unroll
            for (int r = 0; r < 4; r++) {
                int row = bm + wr * 64 + i * 16 + q * 4 + r;
                float v = acc[i][j][r];
                if (WITH_RES) v += res[(size_t)row * N + col];
                C[(size_t)row * N + col] = v;
            }
        }
    }
}

// ---------------------------------------------------------------------------
// qkv prep: split qkv into per-head (NH,S,HD) bf16 q/k/v with l2norm + rope.
// 4 (s,h) pairs per 256-thread block (one per wave).
// ---------------------------------------------------------------------------
__global__ __launch_bounds__(256) void qkv_prep_kernel(
    const float* __restrict__ qkv, unsigned short* __restrict__ qh,
    unsigned short* __restrict__ khb, unsigned short* __restrict__ vhb)
{
    int pair = blockIdx.x * 4 + (threadIdx.x >> 6);
    int s = pair / NH_, h = pair % NH_;
    int lane = threadIdx.x & 63;

    size_t qoff = (size_t)s * (3 * D_) + h * HD_ + lane;
    float qv = qkv[qoff];
    float kv = qkv[qoff + D_];
    float vv = qkv[qoff + 2 * D_];

    float sq = qv * qv, sk = kv * kv;
#pragma unroll
    for (int off = 32; off > 0; off >>= 1) {
        sq += __shfl_xor(sq, off);
        sk += __shfl_xor(sk, off);
    }
    qv /= fmaxf(sqrtf(sq), EPS_);
    kv /= fmaxf(sqrtf(sk), EPS_);

    int j = lane & 31;
    float sign = (lane < 32) ? 1.0f : -1.0f;
    float inv_freq = exp2f((float)j * (-13.287712379549449f / 32.0f));
    float f = (float)s * inv_freq;
    float sn, cs;
    sincosf(f, &sn, &cs);
    float qo = __shfl_xor(qv, 32);
    float ko = __shfl_xor(kv, 32);
    qv = qv * cs + sign * qo * sn;
    kv = kv * cs + sign * ko * sn;

    size_t o = ((size_t)h * S_ + s) * HD_ + lane;
    qh[o]  = f2bf(qv * 0.125f);   // fold 1/sqrt(64)
    khb[o] = f2bf(kv);
    vhb[o] = f2bf(vv);
}

// ---------------------------------------------------------------------------
// MFMA bf16 flash attention, double-buffered LDS + async reg staging.
//   512 blocks, one 64-row q-tile each; heavy/light tile interleave.
// ---------------------------------------------------------------------------
#define FS 72   // shorts per LDS row (pad: 144B rows -> 2-way banks, free)
__global__ __launch_bounds__(256) void flash_attn_mfma_kernel(
    const unsigned short* __restrict__ qh, const unsigned short* __restrict__ khb,
    const unsigned short* __restrict__ vhT, unsigned short* __restrict__ aob)
{
    __shared__ __align__(16) short Ks[2][64][FS];
    __shared__ __align__(16) short Vs[2][64][FS];   // [buf][d][token]
    __shared__ __align__(16) short Ps[4][16][FS];   // per-wave scratch
    int u = blockIdx.x & 255;
    int v = blockIdx.x >> 8;
    int h = u & 15;
    int p = u >> 4;
    int t = v ? (31 - p) : p;
    int tid = threadIdx.x;
    int wq = tid >> 6;
    int lane = tid & 63;
    int ml = lane & 15, quad = lane >> 4;
    int srow = tid >> 2;          // 0..63
    int sc = (tid & 3) * 16;      // 0,16,32,48 (shorts)
    const unsigned short* Qb = qh  + (size_t)h * S_ * HD_;
    const unsigned short* Kb = khb + (size_t)h * S_ * HD_;
    const unsigned short* Vt = vhT + (size_t)h * HD_ * S_;

    int q0 = t * 64;
    int qrow = q0 + wq * 16 + ml;
    s16x8 aq0 = *(const s16x8*)(Qb + (size_t)qrow * HD_ + quad * 8);
    s16x8 aq1 = *(const s16x8*)(Qb + (size_t)qrow * HD_ + 32 + quad * 8);

    float m[4], l[4];
    f32x4 o[4];
#pragma unroll
    for (int r = 0; r < 4; r++) { m[r] = -INFINITY; l[r] = 0.f; }
#pragma unroll
    for (int nb = 0; nb < 4; nb++) o[nb] = (f32x4){0.f, 0.f, 0.f, 0.f};

    int4 kr0, kr1, vr0, vr1;      // staging registers
    // prologue: tile 0 -> buf 0
    {
        const unsigned short* kp = Kb + (size_t)srow * HD_ + sc;
        kr0 = *(const int4*)kp; kr1 = *(const int4*)(kp + 8);
        const unsigned short* vp = Vt + (size_t)srow * S_ + sc;
        vr0 = *(const int4*)vp; vr1 = *(const int4*)(vp + 8);
        *(int4*)(&Ks[0][srow][sc]) = kr0; *(int4*)(&Ks[0][srow][sc + 8]) = kr1;
        *(int4*)(&Vs[0][srow][sc]) = vr0; *(int4*)(&Vs[0][srow][sc + 8]) = vr1;
    }
    __syncthreads();
    int cur = 0;

    for (int kt = 0; kt <= t; kt++) {
        int k0 = kt * 64;
        // issue next tile's global loads early (latency hides under compute)
        if (kt < t) {
            const unsigned short* kp = Kb + (size_t)(k0 + 64 + srow) * HD_ + sc;
            kr0 = *(const int4*)kp; kr1 = *(const int4*)(kp + 8);
            const unsigned short* vp = Vt + (size_t)srow * S_ + k0 + 64 + sc;
            vr0 = *(const int4*)vp; vr1 = *(const int4*)(vp + 8);
        }

        f32x4 s[4];
#pragma unroll
        for (int nb = 0; nb < 4; nb++) s[nb] = (f32x4){0.f, 0.f, 0.f, 0.f};
        __builtin_amdgcn_s_setprio(1);
#pragma unroll
        for (int nb = 0; nb < 4; nb++) {
            s16x8 b0 = *(const s16x8*)(&Ks[cur][nb * 16 + ml][quad * 8]);
            s16x8 b1 = *(const s16x8*)(&Ks[cur][nb * 16 + ml][32 + quad * 8]);
            s[nb] = __builtin_amdgcn_mfma_f32_16x16x32_bf16(aq0, b0, s[nb], 0, 0, 0);
            s[nb] = __builtin_amdgcn_mfma_f32_16x16x32_bf16(aq1, b1, s[nb], 0, 0, 0);
        }
        __builtin_amdgcn_s_setprio(0);

        float sv[4][4];
#pragma unroll
        for (int nb = 0; nb < 4; nb++)
#pragma unroll
            for (int r = 0; r < 4; r++) {
                float val = s[nb][r];
                if (kt == t && (nb * 16 + ml) > (wq * 16 + quad * 4 + r))
                    val = -1e30f;
                sv[nb][r] = val;
            }
#pragma unroll
        for (int r = 0; r < 4; r++) {
            float rm = fmaxf(fmaxf(sv[0][r], sv[1][r]),
                             fmaxf(sv[2][r], sv[3][r]));
#pragma unroll
            for (int off = 1; off < 16; off <<= 1)
                rm = fmaxf(rm, __shfl_xor(rm, off));
            float mn = fmaxf(m[r], rm);
            float corr = __expf(m[r] - mn);
            m[r] = mn;
            float rs = 0.f;
#pragma unroll
            for (int nb = 0; nb < 4; nb++) {
                float pe = __expf(sv[nb][r] - mn);
                sv[nb][r] = pe;
                rs += pe;
            }
#pragma unroll
            for (int off = 1; off < 16; off <<= 1)
                rs += __shfl_xor(rs, off);
            l[r] = l[r] * corr + rs;
#pragma unroll
            for (int nb = 0; nb < 4; nb++) o[nb][r] *= corr;
        }

        // intra-wave P exchange (no barriers: per-wave LDS slice, in-order)
#pragma unroll
        for (int nb = 0; nb < 4; nb++)
#pragma unroll
            for (int r = 0; r < 4; r++)
                Ps[wq][quad * 4 + r][nb * 16 + ml] = (short)f2bf(sv[nb][r]);

        s16x8 ap0 = *(const s16x8*)(&Ps[wq][ml][quad * 8]);
        s16x8 ap1 = *(const s16x8*)(&Ps[wq][ml][32 + quad * 8]);
        __builtin_amdgcn_s_setprio(1);
#pragma unroll
        for (int nb = 0; nb < 4; nb++) {
            s16x8 b0 = *(const s16x8*)(&Vs[cur][nb * 16 + ml][quad * 8]);
            s16x8 b1 = *(const s16x8*)(&Vs[cur][nb * 16 + ml][32 + quad * 8]);
            o[nb] = __builtin_amdgcn_mfma_f32_16x16x32_bf16(ap0, b0, o[nb], 0, 0, 0);
            o[nb] = __builtin_amdgcn_mfma_f32_16x16x32_bf16(ap1, b1, o[nb], 0, 0, 0);
        }
        __builtin_amdgcn_s_setprio(0);

        __syncthreads();                       // B1: reads of buf[cur] done
        if (kt < t) {
            *(int4*)(&Ks[cur ^ 1][srow][sc])     = kr0;
            *(int4*)(&Ks[cur ^ 1][srow][sc + 8]) = kr1;
            *(int4*)(&Vs[cur ^ 1][srow][sc])     = vr0;
            *(int4*)(&Vs[cur ^ 1][srow][sc + 8]) = vr1;
            __syncthreads();                   // B2: buf[cur^1] visible
            cur ^= 1;
        }
    }

#pragma unroll
    for (int r = 0; r < 4; r++) {
        float inv = 1.0f / l[r];
        int row = q0 + wq * 16 + quad * 4 + r;
#pragma unroll
        for (int nb = 0; nb < 4; nb++)
            aob[(size_t)row * D_ + h * HD_ + nb * 16 + ml] =
                f2bf(o[nb][r] * inv);
    }
}

// ---------------------------------------------------------------------------
// gather keys columns into compact bf16 buffer.
// ---------------------------------------------------------------------------
__global__ __launch_bounds__(256) void gather_keys_kernel(
    const float* __restrict__ keys, const int* __restrict__ indices,
    unsigned short* __restrict__ kgath)
{
    int bid = blockIdx.x;
    int pair = bid >> 3, kh = bid & 7;
    int idx = indices[pair];
    int tid = threadIdx.x;
    const float* kp = keys + (size_t)kh * D_ * E_ + idx;
    int d = tid * 4;
    ushort4 o;
    o.x = f2bf(kp[(size_t)(d + 0) * E_]);
    o.y = f2bf(kp[(size_t)(d + 1) * E_]);
    o.z = f2bf(kp[(size_t)(d + 2) * E_]);
    o.w = f2bf(kp[(size_t)(d + 3) * E_]);
    *(ushort4*)(kgath + ((size_t)pair * KH_ + kh) * D_ + d) = o;
}

// ---------------------------------------------------------------------------
// expert score GEMM, split-K x8: block = (chunk c, k-slice sk).
// msbufp[(c*8+sk)][128 t][128 n] fp32 partial = xfb[...][sk*128..+128) @
//   kgath[...][sk*128..+128)^T.  Partials summed in moe prologue.
// ---------------------------------------------------------------------------
__global__ __launch_bounds__(256) void score_gemm_kernel(
    const unsigned short* __restrict__ xfb, const unsigned short* __restrict__ kgath,
    float* __restrict__ msbufp)
{
    __shared__ __align__(16) short As[128][32];
    __shared__ __align__(16) short Bs[128][32];
    int c  = blockIdx.x >> 3;
    int sk = blockIdx.x & 7;
    const unsigned short* A  = xfb   + (size_t)c * 128 * D_ + sk * 128;
    const unsigned short* Bt = kgath + (size_t)c * 128 * D_ + sk * 128;
    int tid = threadIdx.x;
    int wave = tid >> 6, lane = tid & 63;
    int ml = lane & 15, q = lane >> 4;
    int wr = wave >> 1, wc = wave & 1;
    int srow = tid >> 2;
    int scol = (tid & 3) * 8;

    f32x4 acc[4][4];
#pragma unroll
    for (int i = 0; i < 4; i++)
#pragma unroll
        for (int j = 0; j < 4; j++) acc[i][j] = (f32x4){0.f, 0.f, 0.f, 0.f};

    const unsigned short* Ap = A  + (size_t)srow * D_ + scol;
    const unsigned short* Bp = Bt + (size_t)srow * D_ + scol;
    short* ldsA0 = &As[wave * 16][0];
    short* ldsA1 = &As[64 + wave * 16][0];
    short* ldsB0 = &Bs[wave * 16][0];
    short* ldsB1 = &Bs[64 + wave * 16][0];

    for (int k0 = 0; k0 < 128; k0 += 32) {
        __syncthreads();
        GLOAD16(Ap + k0, ldsA0);
        GLOAD16(Ap + (size_t)64 * D_ + k0, ldsA1);
        GLOAD16(Bp + k0, ldsB0);
        GLOAD16(Bp + (size_t)64 * D_ + k0, ldsB1);
        __syncthreads();

        s16x8 af[4], bf[4];
#pragma unroll
        for (int i = 0; i < 4; i++)
            af[i] = *(const s16x8*)(&As[wr * 64 + i * 16 + ml][q * 8]);
#pragma unroll
        for (int j = 0; j < 4; j++)
            bf[j] = *(const s16x8*)(&Bs[wc * 64 + j * 16 + ml][q * 8]);
#pragma unroll
        for (int i = 0; i < 4; i++)
#pragma unroll
            for (int j = 0; j < 4; j++)
                acc[i][j] = __builtin_amdgcn_mfma_f32_16x16x32_bf16(
                    af[i], bf[j], acc[i][j], 0, 0, 0);
    }

    float* out = msbufp + (size_t)blockIdx.x * 128 * 128;
#pragma unroll
    for (int i = 0; i < 4; i++)
#pragma unroll
        for (int j = 0; j < 4; j++) {
            int col = wc * 64 + j * 16 + ml;
#pragma unroll
            for (int r = 0; r < 4; r++) {
                int row = wr * 64 + i * 16 + q * 4 + r;
                out[(size_t)row * 128 + col] = acc[i][j][r];
            }
        }
}

// ---------------------------------------------------------------------------
// gather sp0/sp1/hp per (chunk, e, h) into coalesced spbuf[c][3][256]
// ---------------------------------------------------------------------------
__global__ __launch_bounds__(256) void gather_sp_kernel(
    const float* __restrict__ score_probs, const float* __restrict__ head_probs,
    const int* __restrict__ indices, float* __restrict__ spbuf)
{
    int c = blockIdx.x, tid = threadIdx.x;
    int e = tid >> 4, h = tid & 15;
    int idx = indices[c * ET_ + e];
    int r = e >> 2;   // e / DE_
    float v0 = score_probs[((size_t)(0 * RE_ + r) * E_ + idx) * H_ + h];
    float v1 = score_probs[((size_t)(1 * RE_ + r) * E_ + idx) * H_ + h];
    float v2 = head_probs[((size_t)r * E_ + idx) * H_ + h];
    float* sp = spbuf + (size_t)c * 3 * 256;
    sp[tid] = v0;
    sp[256 + tid] = v1;
    sp[512 + tid] = v2;
}

// ---------------------------------------------------------------------------
// MoE with rank-1 experts + fused combine weights. 2 barriers total:
//   phase A: combine weights (16x16 thread map) + stage x in LDS
//   phase B: wave w computes h0/h1/act for experts 4w..4w+3 independently
//   phase C: all threads accumulate w2 over 16 experts
// ---------------------------------------------------------------------------
__global__ __launch_bounds__(256) void moe_kernel(
    const float* __restrict__ xf, const float* __restrict__ xfi,
    const int* __restrict__ indices, const float* __restrict__ msbufp,
    const float* __restrict__ scores, const float* __restrict__ spbuf,
    const float* __restrict__ experts, float* __restrict__ out)
{
    int t = blockIdx.x, tid = threadIdx.x;
    int c = t >> 7;          // /NT_
    int trow = t & 127;
    __shared__ int sidx[ET_];
    __shared__ float sw[ET_];
    __shared__ float sact[ET_];
    __shared__ float sx[D_];
    if (tid < ET_) sidx[tid] = indices[c * ET_ + tid];
    float4 xv = ((const float4*)(xf + (size_t)t * D_))[tid];
    ((float4*)sx)[tid] = xv;
    // ---- combine weights: thread = (e = tid>>4, h = tid&15) ----
    {
        int e = tid >> 4, h = tid & 15;
        const float* mp = msbufp + ((size_t)(c * 8) * 128 + trow) * 128
                                 + e * 8 + (h >> 1);
        float ms = 0.f;
#pragma unroll
        for (int sck = 0; sck < 8; sck++) ms += mp[(size_t)sck * 128 * 128];
        float scv = scores[(size_t)t * (ET_ * H_) + tid];
        const float* sp = spbuf + (size_t)c * 3 * 256;
        float z = sp[tid] * ms + sp[256 + tid] * scv;
        float term = sp[512 + tid] / (1.0f + __expf(-z));
#pragma unroll
        for (int off = 1; off < 16; off <<= 1)
            term += __shfl_xor(term, off);
        if (h == 0) sw[e] = term;
    }
    __syncthreads();   // sx, sw, sidx ready

    int wv = tid >> 6, lane = tid & 63;
#pragma unroll
    for (int ee = 0; ee < 4; ee++) {
        int e = wv * 4 + ee;
        int idx = sidx[e];
        size_t base = (size_t)idx * D_;
        float p0 = 0.f, p1 = 0.f;
#pragma unroll
        for (int rr = 0; rr < 4; rr++) {
            int dd = rr * 256 + lane * 4;
            float4 xr = *(const float4*)(sx + dd);
            float4 w0 = *(const float4*)(experts + base + dd);
            float4 w1 = *(const float4*)(experts + (size_t)E_ * D_ + base + dd);
            p0 += xr.x*w0.x + xr.y*w0.y + xr.z*w0.z + xr.w*w0.w;
            p1 += xr.x*w1.x + xr.y*w1.y + xr.z*w1.z + xr.w*w1.w;
        }
#pragma unroll
        for (int off = 32; off > 0; off >>= 1) {
            p0 += __shfl_xor(p0, off);
            p1 += __shfl_xor(p1, off);
        }
        if (lane == 0)
            sact[e] = p0 / (1.0f + __expf(-p0)) * p1 * sw[e];
    }
    __syncthreads();   // sact ready

    float a0 = 0.f, a1 = 0.f, a2 = 0.f, a3 = 0.f;
    const float* w2base = experts + (size_t)2 * E_ * D_;
#pragma unroll
    for (int e = 0; e < ET_; e++) {
        float act = sact[e];
        float4 w2 = *(const float4*)(w2base + (size_t)sidx[e] * D_ + tid * 4);
        a0 += act * w2.x;
        a1 += act * w2.y;
        a2 += act * w2.z;
        a3 += act * w2.w;
    }
    size_t o = (size_t)t * D_ + tid * 4;
    float4 rv = *(const float4*)(xfi + o);
    float4 ov;
    ov.x = a0 + rv.x;
    ov.y = a1 + rv.y;
    ov.z = a2 + rv.z;
    ov.w = a3 + rv.w;
    *(float4*)(out + o) = ov;
}

// ---------------------------------------------------------------------------
extern "C" void kernel_launch(void* const* d_in, const int* in_sizes, int n_in,
                              void* d_out, int out_size, void* d_ws, size_t ws_size,
                              hipStream_t stream)
{
    (void)in_sizes; (void)n_in; (void)out_size; (void)ws_size;
    const float* x_input     = (const float*)d_in[0];
    const int*   indices     = (const int*)d_in[1];
    const float* scores      = (const float*)d_in[2];
    const float* attn_w      = (const float*)d_in[3];
    const float* attn_out_w  = (const float*)d_in[4];
    const float* attn_norm_w = (const float*)d_in[5];
    const float* ffn_norm_w  = (const float*)d_in[6];
    const float* ffn_experts = (const float*)d_in[7];
    const float* keys        = (const float*)d_in[8];
    const float* head_probs  = (const float*)d_in[9];
    const float* score_probs = (const float*)d_in[10];
    float* out = (float*)d_out;

    float* ws = (float*)d_ws;
    const size_t MF = 1024 * 1024;
    // Region map (floats), peak 14M floats = 56 MB:
    // A [0,6M): qkv (gemm1 out); after qkv_prep reused as:
    //    aob [0,1M) bf16 | xfi [1M,3M) | xf [3M,5M) | woutT [5M,5.5M) bf16
    // B [6M,8M): xnb bf16 (1-3) -> qh bf16 (4-5) -> xfb bf16 (8+)
    // C [8M,10M): wqkvT bf16 (2-3) -> khb bf16 (4+)
    // D [10M,11M): vhb bf16 (4-4.5) -> kgath bf16 (7.5+)
    // E [11M,12M): vhT bf16 (4.5-5)
    // F [12M,14M): msbufp fp32 (8 x 16 x 128 x 128 partials)
    // G [14M,+12K): spbuf
    float* qkv            = ws;
    unsigned short* aob   = (unsigned short*)ws;
    float* xfi            = ws + 1 * MF;
    float* xf             = ws + 3 * MF;
    unsigned short* woutT = (unsigned short*)(ws + 5 * MF);
    unsigned short* xnb   = (unsigned short*)(ws + 6 * MF);
    unsigned short* qh    = (unsigned short*)(ws + 6 * MF);
    unsigned short* xfb   = (unsigned short*)(ws + 6 * MF);
    unsigned short* wqkvT = (unsigned short*)(ws + 8 * MF);
    unsigned short* khb   = (unsigned short*)(ws + 8 * MF);
    unsigned short* vhb   = (unsigned short*)(ws + 10 * MF);
    unsigned short* kgath = (unsigned short*)(ws + 10 * MF);  // after flash
    unsigned short* vhT   = (unsigned short*)(ws + 11 * MF);
    float* msbufp         = ws + 12 * MF;
    float* spbuf          = ws + 14 * MF;

    // 1) rmsnorm -> bf16
    rmsnorm_bf16_kernel<<<T_, 256, 0, stream>>>(x_input, attn_norm_w, xnb);

    // 2) attn_w (1024 x 3072) -> wqkvT [3072][1024] bf16
    {
        dim3 g(3 * D_ / 32, D_ / 32);
        convt_kernel<<<g, 256, 0, stream>>>(attn_w, wqkvT, D_, 3 * D_);
    }

    // 3) qkv = xnb @ attn_w   (MFMA, global_load_lds staging)
    {
        dim3 g(3 * D_ / 128, T_ / 128);
        mfma_gemm_kernel<0><<<g, 256, 0, stream>>>(xnb, wqkvT, nullptr, qkv,
                                                   T_, 3 * D_, D_);
    }

    // 4) split + l2norm + rope -> bf16 q/k/v
    qkv_prep_kernel<<<T_ * NH_ / 4, 256, 0, stream>>>(qkv, qh, khb, vhb);

    // 4.5) transpose V: vhb [h][s][d] -> vhT [h][d][s]
    {
        dim3 g(HD_ / 32, S_ / 32, NH_);
        transpose_v_kernel<<<g, 256, 0, stream>>>(vhb, vhT);
    }

    // 5) MFMA flash attention -> aob bf16
    flash_attn_mfma_kernel<<<(S_ / 64) * NH_, 256, 0, stream>>>(qh, khb, vhT, aob);

    // 6) attn_out_w (1024 x 1024) -> woutT [1024][1024] bf16
    {
        dim3 g(D_ / 32, D_ / 32);
        convt_kernel<<<g, 256, 0, stream>>>(attn_out_w, woutT, D_, D_);
    }

    // 7) xfi = aob @ attn_out_w + x_input   (MFMA + residual)
    {
        dim3 g(D_ / 128, T_ / 128);
        mfma_gemm_kernel<1><<<g, 256, 0, stream>>>(aob, woutT, x_input, xfi,
                                                   T_, D_, D_);
    }

    // 7.5) gather keys columns (vhb dead after step 4.5)
    gather_keys_kernel<<<BC_ * ET_ * KH_, 256, 0, stream>>>(keys, indices, kgath);

    // 8) rmsnorm dual: xf fp32 + xfb bf16
    rmsnorm_dual_kernel<<<T_, 256, 0, stream>>>(xfi, ffn_norm_w, xf, xfb);

    // 9a) expert score GEMM, split-K x8 -> msbufp partials
    score_gemm_kernel<<<BC_ * 8, 256, 0, stream>>>(xfb, kgath, msbufp);

    // 9b) gather sp0/sp1/hp -> spbuf
    gather_sp_kernel<<<BC_, 256, 0, stream>>>(score_probs, head_probs,
                                              indices, spbuf);

    // 10) MoE (fused combine weights, 2-barrier structure) + final residual
    moe_kernel<<<T_, 256, 0, stream>>>(xf, xfi, indices, msbufp, scores, spbuf,
                                       ffn_experts, out);
}

// Round 4
// 396.904 us; speedup vs baseline: 1.2211x; 1.0346x over previous
//
#include <hip/hip_runtime.h>
#include <hip/hip_bf16.h>
#include <math.h>

// Problem constants
#define D_   1024
#define HD_  64
#define NH_  16
#define H_   16
#define KH_  8
#define NT_  128      // tokens per chunk (N)
#define E_   4096
#define RE_  4
#define DE_  4
#define ET_  16
#define S_   2048
#define T_   2048
#define BC_  16
#define EPS_ 1e-5f

typedef short s16x8 __attribute__((ext_vector_type(8)));
typedef float f32x4 __attribute__((ext_vector_type(4)));

__device__ __forceinline__ unsigned short f2bf(float f) {
    union { float f; unsigned int u; } v; v.f = f;
    unsigned int r = (v.u + 0x7fffu + ((v.u >> 16) & 1u)) >> 16;  // RNE
    return (unsigned short)r;
}

// async global->LDS, 16B per lane; LDS dest is wave-uniform base + lane*16.
#define GLOAD16(gp, lp) __builtin_amdgcn_global_load_lds(                      \
    (__attribute__((address_space(1))) void*)(gp),                             \
    (__attribute__((address_space(3))) void*)(lp), 16, 0, 0)

// ---------------------------------------------------------------------------
// Mega-preprocess (input-only dependencies), one launch:
//   [0,2048):    rmsnorm(x_input) -> xnb bf16
//   [2048,5120): convt attn_w (1024x3072) -> wqkvT [3072][1024] bf16
//   [5120,6144): convt attn_out_w (1024x1024) -> woutT [1024][1024] bf16
//   [6144,8192): gather keys columns -> kgath bf16
// ---------------------------------------------------------------------------
__global__ __launch_bounds__(256) void preprocess_kernel(
    const float* __restrict__ x, const float* __restrict__ attn_norm_w,
    unsigned short* __restrict__ xnb,
    const float* __restrict__ attn_w, unsigned short* __restrict__ wqkvT,
    const float* __restrict__ attn_out_w, unsigned short* __restrict__ woutT,
    const float* __restrict__ keys, const int* __restrict__ indices,
    unsigned short* __restrict__ kgath)
{
    __shared__ float tile[32][33];
    __shared__ float sred[4];
    int bid = blockIdx.x, tid = threadIdx.x;

    if (bid < 2048) {
        // ---- rmsnorm -> bf16 ----
        int row = bid;
        float4 v = ((const float4*)(x + (size_t)row * D_))[tid];
        float ss = v.x*v.x + v.y*v.y + v.z*v.z + v.w*v.w;
#pragma unroll
        for (int off = 32; off > 0; off >>= 1) ss += __shfl_xor(ss, off);
        if ((tid & 63) == 0) sred[tid >> 6] = ss;
        __syncthreads();
        float tot = sred[0] + sred[1] + sred[2] + sred[3];
        float scale = rsqrtf(tot * (1.0f / D_) + EPS_);
        float4 wv = ((const float4*)attn_norm_w)[tid];
        ushort4 o;
        o.x = f2bf(v.x * scale * wv.x);
        o.y = f2bf(v.y * scale * wv.y);
        o.z = f2bf(v.z * scale * wv.z);
        o.w = f2bf(v.w * scale * wv.w);
        *(ushort4*)(xnb + (size_t)row * D_ + tid * 4) = o;
    } else if (bid < 6144) {
        // ---- convert + transpose weight ----
        const float* src; unsigned short* dst; int R, Ncols, bx, by;
        if (bid < 5120) {
            int cid = bid - 2048;
            src = attn_w; dst = wqkvT; R = D_; Ncols = 3 * D_;
            bx = (cid % 96) * 32; by = (cid / 96) * 32;
        } else {
            int cid = bid - 5120;
            src = attn_out_w; dst = woutT; R = D_; Ncols = D_;
            bx = (cid & 31) * 32; by = (cid >> 5) * 32;
        }
        int tx = tid & 31, ty = tid >> 5;
#pragma unroll
        for (int rr = 0; rr < 32; rr += 8)
            tile[ty + rr][tx] = src[(size_t)(by + ty + rr) * Ncols + bx + tx];
        __syncthreads();
#pragma unroll
        for (int rr = 0; rr < 32; rr += 8)
            dst[(size_t)(bx + ty + rr) * R + by + tx] = f2bf(tile[tx][ty + rr]);
    } else {
        // ---- gather keys columns ----
        int gid = bid - 6144;
        int pair = gid >> 3, kh = gid & 7;
        int idx = indices[pair];
        const float* kp = keys + (size_t)kh * D_ * E_ + idx;
        int d = tid * 4;
        ushort4 o;
        o.x = f2bf(kp[(size_t)(d + 0) * E_]);
        o.y = f2bf(kp[(size_t)(d + 1) * E_]);
        o.z = f2bf(kp[(size_t)(d + 2) * E_]);
        o.w = f2bf(kp[(size_t)(d + 3) * E_]);
        *(ushort4*)(kgath + ((size_t)pair * KH_ + kh) * D_ + d) = o;
    }
}

// rmsnorm dual: fp32 out + bf16 out
__global__ __launch_bounds__(256) void rmsnorm_dual_kernel(
    const float* __restrict__ x, const float* __restrict__ w,
    float* __restrict__ out, unsigned short* __restrict__ outb)
{
    int row = blockIdx.x, tid = threadIdx.x;
    __shared__ float sred[4];
    float4 v = ((const float4*)(x + (size_t)row * D_))[tid];
    float ss = v.x*v.x + v.y*v.y + v.z*v.z + v.w*v.w;
#pragma unroll
    for (int off = 32; off > 0; off >>= 1) ss += __shfl_xor(ss, off);
    if ((tid & 63) == 0) sred[tid >> 6] = ss;
    __syncthreads();
    float tot = sred[0] + sred[1] + sred[2] + sred[3];
    float scale = rsqrtf(tot * (1.0f / D_) + EPS_);
    float4 wv = ((const float4*)w)[tid];
    float4 o;
    o.x = v.x * scale * wv.x;
    o.y = v.y * scale * wv.y;
    o.z = v.z * scale * wv.z;
    o.w = v.w * scale * wv.w;
    ((float4*)(out + (size_t)row * D_))[tid] = o;
    ushort4 ob;
    ob.x = f2bf(o.x); ob.y = f2bf(o.y); ob.z = f2bf(o.z); ob.w = f2bf(o.w);
    *(ushort4*)(outb + (size_t)row * D_ + tid * 4) = ob;
}

// ---------------------------------------------------------------------------
// bf16 transpose: vhb [NH][S][HD] -> vhT [NH][HD][S]
// ---------------------------------------------------------------------------
__global__ __launch_bounds__(256) void transpose_v_kernel(
    const unsigned short* __restrict__ src, unsigned short* __restrict__ dst)
{
    __shared__ unsigned short tile[32][34];
    int h  = blockIdx.z;
    int d0 = blockIdx.x * 32;   // HD/32 = 2
    int s0 = blockIdx.y * 32;   // S/32 = 64
    int tx = threadIdx.x & 31, ty = threadIdx.x >> 5;
    const unsigned short* sp = src + ((size_t)h * S_ + s0) * HD_ + d0;
#pragma unroll
    for (int rr = 0; rr < 32; rr += 8)
        tile[ty + rr][tx] = sp[(size_t)(ty + rr) * HD_ + tx];
    __syncthreads();
    unsigned short* dp = dst + ((size_t)h * HD_ + d0) * S_ + s0;
#pragma unroll
    for (int rr = 0; rr < 32; rr += 8)
        dp[(size_t)(ty + rr) * S_ + tx] = tile[tx][ty + rr];
}

// ---------------------------------------------------------------------------
// MFMA GEMM: C[M,N] fp32 = A[M,K] bf16 @ Bt[N,K] bf16 (+ res fp32)
// m97 structure: global_load_lds width-16 staging into linear LDS [128][32].
// ---------------------------------------------------------------------------
template <int WITH_RES>
__global__ __launch_bounds__(256) void mfma_gemm_kernel(
    const unsigned short* __restrict__ A, const unsigned short* __restrict__ Bt,
    const float* __restrict__ res, float* __restrict__ C,
    int M, int N, int K)
{
    __shared__ __align__(16) short As[128][32];
    __shared__ __align__(16) short Bs[128][32];
    int tid = threadIdx.x;
    int wave = tid >> 6, lane = tid & 63;
    int ml = lane & 15, q = lane >> 4;
    int wr = wave >> 1, wc = wave & 1;
    int bm = blockIdx.y * 128, bn = blockIdx.x * 128;
    int srow = tid >> 2;           // 0..63
    int scol = (tid & 3) * 8;      // shorts

    f32x4 acc[4][4];
#pragma unroll
    for (int i = 0; i < 4; i++)
#pragma unroll
        for (int j = 0; j < 4; j++) acc[i][j] = (f32x4){0.f, 0.f, 0.f, 0.f};

    const unsigned short* Ap = A  + (size_t)(bm + srow) * K + scol;
    const unsigned short* Bp = Bt + (size_t)(bn + srow) * K + scol;
    short* ldsA0 = &As[wave * 16][0];
    short* ldsA1 = &As[64 + wave * 16][0];
    short* ldsB0 = &Bs[wave * 16][0];
    short* ldsB1 = &Bs[64 + wave * 16][0];

    for (int k0 = 0; k0 < K; k0 += 32) {
        __syncthreads();
        GLOAD16(Ap + k0, ldsA0);
        GLOAD16(Ap + (size_t)64 * K + k0, ldsA1);
        GLOAD16(Bp + k0, ldsB0);
        GLOAD16(Bp + (size_t)64 * K + k0, ldsB1);
        __syncthreads();

        s16x8 af[4], bf[4];
#pragma unroll
        for (int i = 0; i < 4; i++)
            af[i] = *(const s16x8*)(&As[wr * 64 + i * 16 + ml][q * 8]);
#pragma unroll
        for (int j = 0; j < 4; j++)
            bf[j] = *(const s16x8*)(&Bs[wc * 64 + j * 16 + ml][q * 8]);
#pragma unroll
        for (int i = 0; i < 4; i++)
#pragma unroll
            for (int j = 0; j < 4; j++)
                acc[i][j] = __builtin_amdgcn_mfma_f32_16x16x32_bf16(
                    af[i], bf[j], acc[i][j], 0, 0, 0);
    }

#pragma unroll
    for (int i = 0; i < 4; i++) {
#pragma unroll
        for (int j = 0; j < 4; j++) {
            int col = bn + wc * 64 + j * 16 + ml;
#pragma unroll
            for (int r = 0; r < 4; r++) {
                int row = bm + wr * 64 + i * 16 + q * 4 + r;
                float v = acc[i][j][r];
                if (WITH_RES) v += res[(size_t)row * N + col];
                C[(size_t)row * N + col] = v;
            }
        }
    }
}

// ---------------------------------------------------------------------------
// Fused QKV GEMM: qkv = xnb @ wqkvT^T with epilogue l2norm + rope + split to
// per-head bf16 q/k/v.  Wave wc owns exactly one head's 64 columns, so the
// per-(token,head) L2-norm is in-lane(4) + shfl over 16 ml lanes, and the
// RoPE partner d^32 is register j^2 in the SAME lane.
//   grid (24, 16); blockIdx.x: [0,8)=q, [8,16)=k, [16,24)=v.
// ---------------------------------------------------------------------------
__global__ __launch_bounds__(256) void mfma_gemm_qkv_kernel(
    const unsigned short* __restrict__ A, const unsigned short* __restrict__ Bt,
    unsigned short* __restrict__ qh, unsigned short* __restrict__ khb,
    unsigned short* __restrict__ vhb)
{
    const int K = D_;
    __shared__ __align__(16) short As[128][32];
    __shared__ __align__(16) short Bs[128][32];
    int tid = threadIdx.x;
    int wave = tid >> 6, lane = tid & 63;
    int ml = lane & 15, q = lane >> 4;
    int wr = wave >> 1, wc = wave & 1;
    int bm = blockIdx.y * 128, bn = blockIdx.x * 128;
    int srow = tid >> 2;
    int scol = (tid & 3) * 8;

    f32x4 acc[4][4];
#pragma unroll
    for (int i = 0; i < 4; i++)
#pragma unroll
        for (int j = 0; j < 4; j++) acc[i][j] = (f32x4){0.f, 0.f, 0.f, 0.f};

    const unsigned short* Ap = A  + (size_t)(bm + srow) * K + scol;
    const unsigned short* Bp = Bt + (size_t)(bn + srow) * K + scol;
    short* ldsA0 = &As[wave * 16][0];
    short* ldsA1 = &As[64 + wave * 16][0];
    short* ldsB0 = &Bs[wave * 16][0];
    short* ldsB1 = &Bs[64 + wave * 16][0];

    for (int k0 = 0; k0 < K; k0 += 32) {
        __syncthreads();
        GLOAD16(Ap + k0, ldsA0);
        GLOAD16(Ap + (size_t)64 * K + k0, ldsA1);
        GLOAD16(Bp + k0, ldsB0);
        GLOAD16(Bp + (size_t)64 * K + k0, ldsB1);
        __syncthreads();

        s16x8 af[4], bf[4];
#pragma unroll
        for (int i = 0; i < 4; i++)
            af[i] = *(const s16x8*)(&As[wr * 64 + i * 16 + ml][q * 8]);
#pragma unroll
        for (int j = 0; j < 4; j++)
            bf[j] = *(const s16x8*)(&Bs[wc * 64 + j * 16 + ml][q * 8]);
#pragma unroll
        for (int i = 0; i < 4; i++)
#pragma unroll
            for (int j = 0; j < 4; j++)
                acc[i][j] = __builtin_amdgcn_mfma_f32_16x16x32_bf16(
                    af[i], bf[j], acc[i][j], 0, 0, 0);
    }

    // ---- epilogue: l2norm + rope + bf16 split write ----
    int sel = blockIdx.x >> 3;                  // 0:q 1:k 2:v
    int h = ((blockIdx.x & 7) << 1) + wc;       // head for this wave
    unsigned short* dst = (sel == 0) ? qh : (sel == 1) ? khb : vhb;
    float qscale = (sel == 0) ? 0.125f : 1.0f;  // fold 1/sqrt(64) into q
    float if0 = exp2f((float)ml * (-13.287712379549449f / 32.0f));
    float if1 = exp2f((float)(16 + ml) * (-13.287712379549449f / 32.0f));

#pragma unroll
    for (int i = 0; i < 4; i++) {
#pragma unroll
        for (int r = 0; r < 4; r++) {
            int row = bm + wr * 64 + i * 16 + q * 4 + r;
            float v0 = acc[i][0][r], v1 = acc[i][1][r];
            float v2 = acc[i][2][r], v3 = acc[i][3][r];
            if (sel < 2) {
                float ss = v0*v0 + v1*v1 + v2*v2 + v3*v3;
#pragma unroll
                for (int off = 1; off < 16; off <<= 1)
                    ss += __shfl_xor(ss, off);
                float inv = qscale / fmaxf(sqrtf(ss), EPS_);
                v0 *= inv; v1 *= inv; v2 *= inv; v3 *= inv;
                float sn0, cs0, sn1, cs1;
                sincosf((float)row * if0, &sn0, &cs0);
                sincosf((float)row * if1, &sn1, &cs1);
                float o0 = v0 * cs0 + v2 * sn0;
                float o2 = v2 * cs0 - v0 * sn0;
                float o1 = v1 * cs1 + v3 * sn1;
                float o3 = v3 * cs1 - v1 * sn1;
                v0 = o0; v1 = o1; v2 = o2; v3 = o3;
            }
            size_t base = ((size_t)h * S_ + row) * HD_;
            dst[base +      ml] = f2bf(v0);
            dst[base + 16 + ml] = f2bf(v1);
            dst[base + 32 + ml] = f2bf(v2);
            dst[base + 48 + ml] = f2bf(v3);
        }
    }
}

// ---------------------------------------------------------------------------
// MFMA bf16 flash attention, double-buffered LDS + async reg staging.
//   512 blocks, one 64-row q-tile each; heavy/light tile interleave.
// ---------------------------------------------------------------------------
#define FS 72   // shorts per LDS row (pad: 144B rows -> 2-way banks, free)
__global__ __launch_bounds__(256) void flash_attn_mfma_kernel(
    const unsigned short* __restrict__ qh, const unsigned short* __restrict__ khb,
    const unsigned short* __restrict__ vhT, unsigned short* __restrict__ aob)
{
    __shared__ __align__(16) short Ks[2][64][FS];
    __shared__ __align__(16) short Vs[2][64][FS];   // [buf][d][token]
    __shared__ __align__(16) short Ps[4][16][FS];   // per-wave scratch
    int u = blockIdx.x & 255;
    int v = blockIdx.x >> 8;
    int h = u & 15;
    int p = u >> 4;
    int t = v ? (31 - p) : p;
    int tid = threadIdx.x;
    int wq = tid >> 6;
    int lane = tid & 63;
    int ml = lane & 15, quad = lane >> 4;
    int srow = tid >> 2;          // 0..63
    int sc = (tid & 3) * 16;      // 0,16,32,48 (shorts)
    const unsigned short* Qb = qh  + (size_t)h * S_ * HD_;
    const unsigned short* Kb = khb + (size_t)h * S_ * HD_;
    const unsigned short* Vt = vhT + (size_t)h * HD_ * S_;

    int q0 = t * 64;
    int qrow = q0 + wq * 16 + ml;
    s16x8 aq0 = *(const s16x8*)(Qb + (size_t)qrow * HD_ + quad * 8);
    s16x8 aq1 = *(const s16x8*)(Qb + (size_t)qrow * HD_ + 32 + quad * 8);

    float m[4], l[4];
    f32x4 o[4];
#pragma unroll
    for (int r = 0; r < 4; r++) { m[r] = -INFINITY; l[r] = 0.f; }
#pragma unroll
    for (int nb = 0; nb < 4; nb++) o[nb] = (f32x4){0.f, 0.f, 0.f, 0.f};

    int4 kr0, kr1, vr0, vr1;      // staging registers
    // prologue: tile 0 -> buf 0
    {
        const unsigned short* kp = Kb + (size_t)srow * HD_ + sc;
        kr0 = *(const int4*)kp; kr1 = *(const int4*)(kp + 8);
        const unsigned short* vp = Vt + (size_t)srow * S_ + sc;
        vr0 = *(const int4*)vp; vr1 = *(const int4*)(vp + 8);
        *(int4*)(&Ks[0][srow][sc]) = kr0; *(int4*)(&Ks[0][srow][sc + 8]) = kr1;
        *(int4*)(&Vs[0][srow][sc]) = vr0; *(int4*)(&Vs[0][srow][sc + 8]) = vr1;
    }
    __syncthreads();
    int cur = 0;

    for (int kt = 0; kt <= t; kt++) {
        int k0 = kt * 64;
        // issue next tile's global loads early (latency hides under compute)
        if (kt < t) {
            const unsigned short* kp = Kb + (size_t)(k0 + 64 + srow) * HD_ + sc;
            kr0 = *(const int4*)kp; kr1 = *(const int4*)(kp + 8);
            const unsigned short* vp = Vt + (size_t)srow * S_ + k0 + 64 + sc;
            vr0 = *(const int4*)vp; vr1 = *(const int4*)(vp + 8);
        }

        f32x4 s[4];
#pragma unroll
        for (int nb = 0; nb < 4; nb++) s[nb] = (f32x4){0.f, 0.f, 0.f, 0.f};
        __builtin_amdgcn_s_setprio(1);
#pragma unroll
        for (int nb = 0; nb < 4; nb++) {
            s16x8 b0 = *(const s16x8*)(&Ks[cur][nb * 16 + ml][quad * 8]);
            s16x8 b1 = *(const s16x8*)(&Ks[cur][nb * 16 + ml][32 + quad * 8]);
            s[nb] = __builtin_amdgcn_mfma_f32_16x16x32_bf16(aq0, b0, s[nb], 0, 0, 0);
            s[nb] = __builtin_amdgcn_mfma_f32_16x16x32_bf16(aq1, b1, s[nb], 0, 0, 0);
        }
        __builtin_amdgcn_s_setprio(0);

        float sv[4][4];
#pragma unroll
        for (int nb = 0; nb < 4; nb++)
#pragma unroll
            for (int r = 0; r < 4; r++) {
                float val = s[nb][r];
                if (kt == t && (nb * 16 + ml) > (wq * 16 + quad * 4 + r))
                    val = -1e30f;
                sv[nb][r] = val;
            }
#pragma unroll
        for (int r = 0; r < 4; r++) {
            float rm = fmaxf(fmaxf(sv[0][r], sv[1][r]),
                             fmaxf(sv[2][r], sv[3][r]));
#pragma unroll
            for (int off = 1; off < 16; off <<= 1)
                rm = fmaxf(rm, __shfl_xor(rm, off));
            float mn = fmaxf(m[r], rm);
            float corr = __expf(m[r] - mn);
            m[r] = mn;
            float rs = 0.f;
#pragma unroll
            for (int nb = 0; nb < 4; nb++) {
                float pe = __expf(sv[nb][r] - mn);
                sv[nb][r] = pe;
                rs += pe;
            }
#pragma unroll
            for (int off = 1; off < 16; off <<= 1)
                rs += __shfl_xor(rs, off);
            l[r] = l[r] * corr + rs;
#pragma unroll
            for (int nb = 0; nb < 4; nb++) o[nb][r] *= corr;
        }

        // intra-wave P exchange (no barriers: per-wave LDS slice, in-order)
#pragma unroll
        for (int nb = 0; nb < 4; nb++)
#pragma unroll
            for (int r = 0; r < 4; r++)
                Ps[wq][quad * 4 + r][nb * 16 + ml] = (short)f2bf(sv[nb][r]);

        s16x8 ap0 = *(const s16x8*)(&Ps[wq][ml][quad * 8]);
        s16x8 ap1 = *(const s16x8*)(&Ps[wq][ml][32 + quad * 8]);
        __builtin_amdgcn_s_setprio(1);
#pragma unroll
        for (int nb = 0; nb < 4; nb++) {
            s16x8 b0 = *(const s16x8*)(&Vs[cur][nb * 16 + ml][quad * 8]);
            s16x8 b1 = *(const s16x8*)(&Vs[cur][nb * 16 + ml][32 + quad * 8]);
            o[nb] = __builtin_amdgcn_mfma_f32_16x16x32_bf16(ap0, b0, o[nb], 0, 0, 0);
            o[nb] = __builtin_amdgcn_mfma_f32_16x16x32_bf16(ap1, b1, o[nb], 0, 0, 0);
        }
        __builtin_amdgcn_s_setprio(0);

        __syncthreads();                       // B1: reads of buf[cur] done
        if (kt < t) {
            *(int4*)(&Ks[cur ^ 1][srow][sc])     = kr0;
            *(int4*)(&Ks[cur ^ 1][srow][sc + 8]) = kr1;
            *(int4*)(&Vs[cur ^ 1][srow][sc])     = vr0;
            *(int4*)(&Vs[cur ^ 1][srow][sc + 8]) = vr1;
            __syncthreads();                   // B2: buf[cur^1] visible
            cur ^= 1;
        }
    }

#pragma unroll
    for (int r = 0; r < 4; r++) {
        float inv = 1.0f / l[r];
        int row = q0 + wq * 16 + quad * 4 + r;
#pragma unroll
        for (int nb = 0; nb < 4; nb++)
            aob[(size_t)row * D_ + h * HD_ + nb * 16 + ml] =
                f2bf(o[nb][r] * inv);
    }
}

// ---------------------------------------------------------------------------
// expert score GEMM, split-K x8: block = (chunk c, k-slice sk).
// ---------------------------------------------------------------------------
__global__ __launch_bounds__(256) void score_gemm_kernel(
    const unsigned short* __restrict__ xfb, const unsigned short* __restrict__ kgath,
    float* __restrict__ msbufp)
{
    __shared__ __align__(16) short As[128][32];
    __shared__ __align__(16) short Bs[128][32];
    int c  = blockIdx.x >> 3;
    int sk = blockIdx.x & 7;
    const unsigned short* A  = xfb   + (size_t)c * 128 * D_ + sk * 128;
    const unsigned short* Bt = kgath + (size_t)c * 128 * D_ + sk * 128;
    int tid = threadIdx.x;
    int wave = tid >> 6, lane = tid & 63;
    int ml = lane & 15, q = lane >> 4;
    int wr = wave >> 1, wc = wave & 1;
    int srow = tid >> 2;
    int scol = (tid & 3) * 8;

    f32x4 acc[4][4];
#pragma unroll
    for (int i = 0; i < 4; i++)
#pragma unroll
        for (int j = 0; j < 4; j++) acc[i][j] = (f32x4){0.f, 0.f, 0.f, 0.f};

    const unsigned short* Ap = A  + (size_t)srow * D_ + scol;
    const unsigned short* Bp = Bt + (size_t)srow * D_ + scol;
    short* ldsA0 = &As[wave * 16][0];
    short* ldsA1 = &As[64 + wave * 16][0];
    short* ldsB0 = &Bs[wave * 16][0];
    short* ldsB1 = &Bs[64 + wave * 16][0];

    for (int k0 = 0; k0 < 128; k0 += 32) {
        __syncthreads();
        GLOAD16(Ap + k0, ldsA0);
        GLOAD16(Ap + (size_t)64 * D_ + k0, ldsA1);
        GLOAD16(Bp + k0, ldsB0);
        GLOAD16(Bp + (size_t)64 * D_ + k0, ldsB1);
        __syncthreads();

        s16x8 af[4], bf[4];
#pragma unroll
        for (int i = 0; i < 4; i++)
            af[i] = *(const s16x8*)(&As[wr * 64 + i * 16 + ml][q * 8]);
#pragma unroll
        for (int j = 0; j < 4; j++)
            bf[j] = *(const s16x8*)(&Bs[wc * 64 + j * 16 + ml][q * 8]);
#pragma unroll
        for (int i = 0; i < 4; i++)
#pragma unroll
            for (int j = 0; j < 4; j++)
                acc[i][j] = __builtin_amdgcn_mfma_f32_16x16x32_bf16(
                    af[i], bf[j], acc[i][j], 0, 0, 0);
    }

    float* out = msbufp + (size_t)blockIdx.x * 128 * 128;
#pragma unroll
    for (int i = 0; i < 4; i++)
#pragma unroll
        for (int j = 0; j < 4; j++) {
            int col = wc * 64 + j * 16 + ml;
#pragma unroll
            for (int r = 0; r < 4; r++) {
                int row = wr * 64 + i * 16 + q * 4 + r;
                out[(size_t)row * 128 + col] = acc[i][j][r];
            }
        }
}

// ---------------------------------------------------------------------------
// MoE with rank-1 experts + fused combine weights (sp gather inlined).
// ---------------------------------------------------------------------------
__global__ __launch_bounds__(256) void moe_kernel(
    const float* __restrict__ xf, const float* __restrict__ xfi,
    const int* __restrict__ indices, const float* __restrict__ msbufp,
    const float* __restrict__ scores,
    const float* __restrict__ score_probs, const float* __restrict__ head_probs,
    const float* __restrict__ experts, float* __restrict__ out)
{
    int t = blockIdx.x, tid = threadIdx.x;
    int c = t >> 7;          // /NT_
    int trow = t & 127;
    __shared__ int sidx[ET_];
    __shared__ float sw[ET_];
    __shared__ float sact[ET_];
    __shared__ float sx[D_];
    if (tid < ET_) sidx[tid] = indices[c * ET_ + tid];
    float4 xv = ((const float4*)(xf + (size_t)t * D_))[tid];
    ((float4*)sx)[tid] = xv;
    // ---- combine weights: thread = (e = tid>>4, hh = tid&15) ----
    {
        int e = tid >> 4, hh = tid & 15;
        int idx = indices[c * ET_ + e];
        int rr = e >> 2;   // e / DE_
        const float* mp = msbufp + ((size_t)(c * 8) * 128 + trow) * 128
                                 + e * 8 + (hh >> 1);
        float ms = 0.f;
#pragma unroll
        for (int sck = 0; sck < 8; sck++) ms += mp[(size_t)sck * 128 * 128];
        float scv = scores[(size_t)t * (ET_ * H_) + tid];
        float sp0 = score_probs[((size_t)rr * E_ + idx) * H_ + hh];
        float sp1 = score_probs[((size_t)(RE_ + rr) * E_ + idx) * H_ + hh];
        float hp  = head_probs[((size_t)rr * E_ + idx) * H_ + hh];
        float z = sp0 * ms + sp1 * scv;
        float term = hp / (1.0f + __expf(-z));
#pragma unroll
        for (int off = 1; off < 16; off <<= 1)
            term += __shfl_xor(term, off);
        if (hh == 0) sw[e] = term;
    }
    __syncthreads();   // sx, sw, sidx ready

    int wv = tid >> 6, lane = tid & 63;
#pragma unroll
    for (int ee = 0; ee < 4; ee++) {
        int e = wv * 4 + ee;
        int idx = sidx[e];
        size_t base = (size_t)idx * D_;
        float p0 = 0.f, p1 = 0.f;
#pragma unroll
        for (int rr = 0; rr < 4; rr++) {
            int dd = rr * 256 + lane * 4;
            float4 xr = *(const float4*)(sx + dd);
            float4 w0 = *(const float4*)(experts + base + dd);
            float4 w1 = *(const float4*)(experts + (size_t)E_ * D_ + base + dd);
            p0 += xr.x*w0.x + xr.y*w0.y + xr.z*w0.z + xr.w*w0.w;
            p1 += xr.x*w1.x + xr.y*w1.y + xr.z*w1.z + xr.w*w1.w;
        }
#pragma unroll
        for (int off = 32; off > 0; off >>= 1) {
            p0 += __shfl_xor(p0, off);
            p1 += __shfl_xor(p1, off);
        }
        if (lane == 0)
            sact[e] = p0 / (1.0f + __expf(-p0)) * p1 * sw[e];
    }
    __syncthreads();   // sact ready

    float a0 = 0.f, a1 = 0.f, a2 = 0.f, a3 = 0.f;
    const float* w2base = experts + (size_t)2 * E_ * D_;
#pragma unroll
    for (int e = 0; e < ET_; e++) {
        float act = sact[e];
        float4 w2 = *(const float4*)(w2base + (size_t)sidx[e] * D_ + tid * 4);
        a0 += act * w2.x;
        a1 += act * w2.y;
        a2 += act * w2.z;
        a3 += act * w2.w;
    }
    size_t o = (size_t)t * D_ + tid * 4;
    float4 rv = *(const float4*)(xfi + o);
    float4 ov;
    ov.x = a0 + rv.x;
    ov.y = a1 + rv.y;
    ov.z = a2 + rv.z;
    ov.w = a3 + rv.w;
    *(float4*)(out + o) = ov;
}

// ---------------------------------------------------------------------------
extern "C" void kernel_launch(void* const* d_in, const int* in_sizes, int n_in,
                              void* d_out, int out_size, void* d_ws, size_t ws_size,
                              hipStream_t stream)
{
    (void)in_sizes; (void)n_in; (void)out_size; (void)ws_size;
    const float* x_input     = (const float*)d_in[0];
    const int*   indices     = (const int*)d_in[1];
    const float* scores      = (const float*)d_in[2];
    const float* attn_w      = (const float*)d_in[3];
    const float* attn_out_w  = (const float*)d_in[4];
    const float* attn_norm_w = (const float*)d_in[5];
    const float* ffn_norm_w  = (const float*)d_in[6];
    const float* ffn_experts = (const float*)d_in[7];
    const float* keys        = (const float*)d_in[8];
    const float* head_probs  = (const float*)d_in[9];
    const float* score_probs = (const float*)d_in[10];
    float* out = (float*)d_out;

    float* ws = (float*)d_ws;
    const size_t MF = 1024 * 1024;
    // Region map (floats), peak 14M floats = 56 MB:
    // qh    [0,1M)    bf16     (gemm_qkv -> flash)
    // khb   [1M,2M)   bf16
    // vhb   [2M,3M)   bf16     (gemm_qkv -> transpose_v)
    // vhT   [3M,4M)   bf16     (transpose_v -> flash)
    // xfi   [4M,6M)   f32      (gemm2 -> rmsnorm_dual, moe)
    // xnb   [6M,7M)   bf16     (preprocess -> gemm_qkv); reused: aob (flash->gemm2)
    // woutT [7M,7.5M) bf16     (preprocess -> gemm2)
    // wqkvT [8M,9.5M) bf16     (preprocess -> gemm_qkv); reused: xf [8M,10M) f32
    // kgath [10M,11M) bf16     (preprocess -> score_gemm)
    // xfb   [11M,12M) bf16     (rmsnorm_dual -> score_gemm)
    // msbufp[12M,14M) f32      (score_gemm -> moe)
    unsigned short* qh    = (unsigned short*)ws;
    unsigned short* khb   = (unsigned short*)(ws + 1 * MF);
    unsigned short* vhb   = (unsigned short*)(ws + 2 * MF);
    unsigned short* vhT   = (unsigned short*)(ws + 3 * MF);
    float* xfi            = ws + 4 * MF;
    unsigned short* xnb   = (unsigned short*)(ws + 6 * MF);
    unsigned short* aob   = (unsigned short*)(ws + 6 * MF);
    unsigned short* woutT = (unsigned short*)(ws + 7 * MF);
    unsigned short* wqkvT = (unsigned short*)(ws + 8 * MF);
    float* xf             = ws + 8 * MF;
    unsigned short* kgath = (unsigned short*)(ws + 10 * MF);
    unsigned short* xfb   = (unsigned short*)(ws + 11 * MF);
    float* msbufp         = ws + 12 * MF;

    // 1) mega-preprocess: rmsnorm + weight transposes + key gather
    preprocess_kernel<<<8192, 256, 0, stream>>>(
        x_input, attn_norm_w, xnb, attn_w, wqkvT, attn_out_w, woutT,
        keys, indices, kgath);

    // 2) fused qkv GEMM + l2norm + rope + head split -> qh/khb/vhb bf16
    {
        dim3 g(3 * D_ / 128, T_ / 128);
        mfma_gemm_qkv_kernel<<<g, 256, 0, stream>>>(xnb, wqkvT, qh, khb, vhb);
    }

    // 3) transpose V: vhb [h][s][d] -> vhT [h][d][s]
    {
        dim3 g(HD_ / 32, S_ / 32, NH_);
        transpose_v_kernel<<<g, 256, 0, stream>>>(vhb, vhT);
    }

    // 4) MFMA flash attention -> aob bf16
    flash_attn_mfma_kernel<<<(S_ / 64) * NH_, 256, 0, stream>>>(qh, khb, vhT, aob);

    // 5) xfi = aob @ attn_out_w + x_input   (MFMA + residual)
    {
        dim3 g(D_ / 128, T_ / 128);
        mfma_gemm_kernel<1><<<g, 256, 0, stream>>>(aob, woutT, x_input, xfi,
                                                   T_, D_, D_);
    }

    // 6) rmsnorm dual: xf fp32 + xfb bf16
    rmsnorm_dual_kernel<<<T_, 256, 0, stream>>>(xfi, ffn_norm_w, xf, xfb);

    // 7) expert score GEMM, split-K x8 -> msbufp partials
    score_gemm_kernel<<<BC_ * 8, 256, 0, stream>>>(xfb, kgath, msbufp);

    // 8) MoE (combine weights + sp gather fused) + final residual
    moe_kernel<<<T_, 256, 0, stream>>>(xf, xfi, indices, msbufp, scores,
                                       score_probs, head_probs,
                                       ffn_experts, out);
}

// Round 5
// 375.686 us; speedup vs baseline: 1.2901x; 1.0565x over previous
//
#include <hip/hip_runtime.h>
#include <hip/hip_bf16.h>
#include <math.h>

// Problem constants
#define D_   1024
#define HD_  64
#define NH_  16
#define H_   16
#define KH_  8
#define NT_  128      // tokens per chunk (N)
#define E_   4096
#define RE_  4
#define DE_  4
#define ET_  16
#define S_   2048
#define T_   2048
#define BC_  16
#define EPS_ 1e-5f

typedef short s16x8 __attribute__((ext_vector_type(8)));
typedef float f32x4 __attribute__((ext_vector_type(4)));

__device__ __forceinline__ unsigned short f2bf(float f) {
    union { float f; unsigned int u; } v; v.f = f;
    unsigned int r = (v.u + 0x7fffu + ((v.u >> 16) & 1u)) >> 16;  // RNE
    return (unsigned short)r;
}

// async global->LDS, 16B per lane; LDS dest is wave-uniform base + lane*16.
#define GLOAD16(gp, lp) __builtin_amdgcn_global_load_lds(                      \
    (__attribute__((address_space(1))) void*)(gp),                             \
    (__attribute__((address_space(3))) void*)(lp), 16, 0, 0)

// ---------------------------------------------------------------------------
// Mega-preprocess (input-only dependencies), one launch:
//   [0,2048):    rmsnorm(x_input) -> xnb bf16
//   [2048,5120): convt attn_w (1024x3072) -> wqkvT [3072][1024] bf16
//   [5120,6144): convt attn_out_w (1024x1024) -> woutT [1024][1024] bf16
//   [6144,8192): gather keys columns -> kgath bf16
// ---------------------------------------------------------------------------
__global__ __launch_bounds__(256) void preprocess_kernel(
    const float* __restrict__ x, const float* __restrict__ attn_norm_w,
    unsigned short* __restrict__ xnb,
    const float* __restrict__ attn_w, unsigned short* __restrict__ wqkvT,
    const float* __restrict__ attn_out_w, unsigned short* __restrict__ woutT,
    const float* __restrict__ keys, const int* __restrict__ indices,
    unsigned short* __restrict__ kgath)
{
    __shared__ float tile[32][33];
    __shared__ float sred[4];
    int bid = blockIdx.x, tid = threadIdx.x;

    if (bid < 2048) {
        // ---- rmsnorm -> bf16 ----
        int row = bid;
        float4 v = ((const float4*)(x + (size_t)row * D_))[tid];
        float ss = v.x*v.x + v.y*v.y + v.z*v.z + v.w*v.w;
#pragma unroll
        for (int off = 32; off > 0; off >>= 1) ss += __shfl_xor(ss, off);
        if ((tid & 63) == 0) sred[tid >> 6] = ss;
        __syncthreads();
        float tot = sred[0] + sred[1] + sred[2] + sred[3];
        float scale = rsqrtf(tot * (1.0f / D_) + EPS_);
        float4 wv = ((const float4*)attn_norm_w)[tid];
        ushort4 o;
        o.x = f2bf(v.x * scale * wv.x);
        o.y = f2bf(v.y * scale * wv.y);
        o.z = f2bf(v.z * scale * wv.z);
        o.w = f2bf(v.w * scale * wv.w);
        *(ushort4*)(xnb + (size_t)row * D_ + tid * 4) = o;
    } else if (bid < 6144) {
        // ---- convert + transpose weight ----
        const float* src; unsigned short* dst; int R, Ncols, bx, by;
        if (bid < 5120) {
            int cid = bid - 2048;
            src = attn_w; dst = wqkvT; R = D_; Ncols = 3 * D_;
            bx = (cid % 96) * 32; by = (cid / 96) * 32;
        } else {
            int cid = bid - 5120;
            src = attn_out_w; dst = woutT; R = D_; Ncols = D_;
            bx = (cid & 31) * 32; by = (cid >> 5) * 32;
        }
        int tx = tid & 31, ty = tid >> 5;
#pragma unroll
        for (int rr = 0; rr < 32; rr += 8)
            tile[ty + rr][tx] = src[(size_t)(by + ty + rr) * Ncols + bx + tx];
        __syncthreads();
#pragma unroll
        for (int rr = 0; rr < 32; rr += 8)
            dst[(size_t)(bx + ty + rr) * R + by + tx] = f2bf(tile[tx][ty + rr]);
    } else {
        // ---- gather keys columns ----
        int gid = bid - 6144;
        int pair = gid >> 3, kh = gid & 7;
        int idx = indices[pair];
        const float* kp = keys + (size_t)kh * D_ * E_ + idx;
        int d = tid * 4;
        ushort4 o;
        o.x = f2bf(kp[(size_t)(d + 0) * E_]);
        o.y = f2bf(kp[(size_t)(d + 1) * E_]);
        o.z = f2bf(kp[(size_t)(d + 2) * E_]);
        o.w = f2bf(kp[(size_t)(d + 3) * E_]);
        *(ushort4*)(kgath + ((size_t)pair * KH_ + kh) * D_ + d) = o;
    }
}

// rmsnorm dual: fp32 out + bf16 out
__global__ __launch_bounds__(256) void rmsnorm_dual_kernel(
    const float* __restrict__ x, const float* __restrict__ w,
    float* __restrict__ out, unsigned short* __restrict__ outb)
{
    int row = blockIdx.x, tid = threadIdx.x;
    __shared__ float sred[4];
    float4 v = ((const float4*)(x + (size_t)row * D_))[tid];
    float ss = v.x*v.x + v.y*v.y + v.z*v.z + v.w*v.w;
#pragma unroll
    for (int off = 32; off > 0; off >>= 1) ss += __shfl_xor(ss, off);
    if ((tid & 63) == 0) sred[tid >> 6] = ss;
    __syncthreads();
    float tot = sred[0] + sred[1] + sred[2] + sred[3];
    float scale = rsqrtf(tot * (1.0f / D_) + EPS_);
    float4 wv = ((const float4*)w)[tid];
    float4 o;
    o.x = v.x * scale * wv.x;
    o.y = v.y * scale * wv.y;
    o.z = v.z * scale * wv.z;
    o.w = v.w * scale * wv.w;
    ((float4*)(out + (size_t)row * D_))[tid] = o;
    ushort4 ob;
    ob.x = f2bf(o.x); ob.y = f2bf(o.y); ob.z = f2bf(o.z); ob.w = f2bf(o.w);
    *(ushort4*)(outb + (size_t)row * D_ + tid * 4) = ob;
}

// ---------------------------------------------------------------------------
// bf16 transpose: vhb [NH][S][HD] -> vhT [NH][HD][S]
// ---------------------------------------------------------------------------
__global__ __launch_bounds__(256) void transpose_v_kernel(
    const unsigned short* __restrict__ src, unsigned short* __restrict__ dst)
{
    __shared__ unsigned short tile[32][34];
    int h  = blockIdx.z;
    int d0 = blockIdx.x * 32;   // HD/32 = 2
    int s0 = blockIdx.y * 32;   // S/32 = 64
    int tx = threadIdx.x & 31, ty = threadIdx.x >> 5;
    const unsigned short* sp = src + ((size_t)h * S_ + s0) * HD_ + d0;
#pragma unroll
    for (int rr = 0; rr < 32; rr += 8)
        tile[ty + rr][tx] = sp[(size_t)(ty + rr) * HD_ + tx];
    __syncthreads();
    unsigned short* dp = dst + ((size_t)h * HD_ + d0) * S_ + s0;
#pragma unroll
    for (int rr = 0; rr < 32; rr += 8)
        dp[(size_t)(ty + rr) * S_ + tx] = tile[tx][ty + rr];
}

// ---------------------------------------------------------------------------
// MFMA GEMM: C[M,N] fp32 = A[M,K] bf16 @ Bt[N,K] bf16 (+ res fp32)
// m97 structure: global_load_lds width-16 staging into linear LDS [128][32].
// ---------------------------------------------------------------------------
template <int WITH_RES>
__global__ __launch_bounds__(256) void mfma_gemm_kernel(
    const unsigned short* __restrict__ A, const unsigned short* __restrict__ Bt,
    const float* __restrict__ res, float* __restrict__ C,
    int M, int N, int K)
{
    __shared__ __align__(16) short As[128][32];
    __shared__ __align__(16) short Bs[128][32];
    int tid = threadIdx.x;
    int wave = tid >> 6, lane = tid & 63;
    int ml = lane & 15, q = lane >> 4;
    int wr = wave >> 1, wc = wave & 1;
    int bm = blockIdx.y * 128, bn = blockIdx.x * 128;
    int srow = tid >> 2;           // 0..63
    int scol = (tid & 3) * 8;      // shorts

    f32x4 acc[4][4];
#pragma unroll
    for (int i = 0; i < 4; i++)
#pragma unroll
        for (int j = 0; j < 4; j++) acc[i][j] = (f32x4){0.f, 0.f, 0.f, 0.f};

    const unsigned short* Ap = A  + (size_t)(bm + srow) * K + scol;
    const unsigned short* Bp = Bt + (size_t)(bn + srow) * K + scol;
    short* ldsA0 = &As[wave * 16][0];
    short* ldsA1 = &As[64 + wave * 16][0];
    short* ldsB0 = &Bs[wave * 16][0];
    short* ldsB1 = &Bs[64 + wave * 16][0];

    for (int k0 = 0; k0 < K; k0 += 32) {
        __syncthreads();
        GLOAD16(Ap + k0, ldsA0);
        GLOAD16(Ap + (size_t)64 * K + k0, ldsA1);
        GLOAD16(Bp + k0, ldsB0);
        GLOAD16(Bp + (size_t)64 * K + k0, ldsB1);
        __syncthreads();

        s16x8 af[4], bf[4];
#pragma unroll
        for (int i = 0; i < 4; i++)
            af[i] = *(const s16x8*)(&As[wr * 64 + i * 16 + ml][q * 8]);
#pragma unroll
        for (int j = 0; j < 4; j++)
            bf[j] = *(const s16x8*)(&Bs[wc * 64 + j * 16 + ml][q * 8]);
#pragma unroll
        for (int i = 0; i < 4; i++)
#pragma unroll
            for (int j = 0; j < 4; j++)
                acc[i][j] = __builtin_amdgcn_mfma_f32_16x16x32_bf16(
                    af[i], bf[j], acc[i][j], 0, 0, 0);
    }

#pragma unroll
    for (int i = 0; i < 4; i++) {
#pragma unroll
        for (int j = 0; j < 4; j++) {
            int col = bn + wc * 64 + j * 16 + ml;
#pragma unroll
            for (int r = 0; r < 4; r++) {
                int row = bm + wr * 64 + i * 16 + q * 4 + r;
                float v = acc[i][j][r];
                if (WITH_RES) v += res[(size_t)row * N + col];
                C[(size_t)row * N + col] = v;
            }
        }
    }
}

// ---------------------------------------------------------------------------
// Fused QKV GEMM: qkv = xnb @ wqkvT^T with epilogue l2norm + rope + split to
// per-head bf16 q/k/v.  Wave wc owns exactly one head's 64 columns.
//   grid (24, 16); blockIdx.x: [0,8)=q, [8,16)=k, [16,24)=v.
// ---------------------------------------------------------------------------
__global__ __launch_bounds__(256) void mfma_gemm_qkv_kernel(
    const unsigned short* __restrict__ A, const unsigned short* __restrict__ Bt,
    unsigned short* __restrict__ qh, unsigned short* __restrict__ khb,
    unsigned short* __restrict__ vhb)
{
    const int K = D_;
    __shared__ __align__(16) short As[128][32];
    __shared__ __align__(16) short Bs[128][32];
    int tid = threadIdx.x;
    int wave = tid >> 6, lane = tid & 63;
    int ml = lane & 15, q = lane >> 4;
    int wr = wave >> 1, wc = wave & 1;
    int bm = blockIdx.y * 128, bn = blockIdx.x * 128;
    int srow = tid >> 2;
    int scol = (tid & 3) * 8;

    f32x4 acc[4][4];
#pragma unroll
    for (int i = 0; i < 4; i++)
#pragma unroll
        for (int j = 0; j < 4; j++) acc[i][j] = (f32x4){0.f, 0.f, 0.f, 0.f};

    const unsigned short* Ap = A  + (size_t)(bm + srow) * K + scol;
    const unsigned short* Bp = Bt + (size_t)(bn + srow) * K + scol;
    short* ldsA0 = &As[wave * 16][0];
    short* ldsA1 = &As[64 + wave * 16][0];
    short* ldsB0 = &Bs[wave * 16][0];
    short* ldsB1 = &Bs[64 + wave * 16][0];

    for (int k0 = 0; k0 < K; k0 += 32) {
        __syncthreads();
        GLOAD16(Ap + k0, ldsA0);
        GLOAD16(Ap + (size_t)64 * K + k0, ldsA1);
        GLOAD16(Bp + k0, ldsB0);
        GLOAD16(Bp + (size_t)64 * K + k0, ldsB1);
        __syncthreads();

        s16x8 af[4], bf[4];
#pragma unroll
        for (int i = 0; i < 4; i++)
            af[i] = *(const s16x8*)(&As[wr * 64 + i * 16 + ml][q * 8]);
#pragma unroll
        for (int j = 0; j < 4; j++)
            bf[j] = *(const s16x8*)(&Bs[wc * 64 + j * 16 + ml][q * 8]);
#pragma unroll
        for (int i = 0; i < 4; i++)
#pragma unroll
            for (int j = 0; j < 4; j++)
                acc[i][j] = __builtin_amdgcn_mfma_f32_16x16x32_bf16(
                    af[i], bf[j], acc[i][j], 0, 0, 0);
    }

    // ---- epilogue: l2norm + rope + bf16 split write ----
    int sel = blockIdx.x >> 3;                  // 0:q 1:k 2:v
    int h = ((blockIdx.x & 7) << 1) + wc;       // head for this wave
    unsigned short* dst = (sel == 0) ? qh : (sel == 1) ? khb : vhb;
    float qscale = (sel == 0) ? 0.125f : 1.0f;  // fold 1/sqrt(64) into q
    float if0 = exp2f((float)ml * (-13.287712379549449f / 32.0f));
    float if1 = exp2f((float)(16 + ml) * (-13.287712379549449f / 32.0f));

#pragma unroll
    for (int i = 0; i < 4; i++) {
#pragma unroll
        for (int r = 0; r < 4; r++) {
            int row = bm + wr * 64 + i * 16 + q * 4 + r;
            float v0 = acc[i][0][r], v1 = acc[i][1][r];
            float v2 = acc[i][2][r], v3 = acc[i][3][r];
            if (sel < 2) {
                float ss = v0*v0 + v1*v1 + v2*v2 + v3*v3;
#pragma unroll
                for (int off = 1; off < 16; off <<= 1)
                    ss += __shfl_xor(ss, off);
                float inv = qscale / fmaxf(sqrtf(ss), EPS_);
                v0 *= inv; v1 *= inv; v2 *= inv; v3 *= inv;
                float sn0, cs0, sn1, cs1;
                sincosf((float)row * if0, &sn0, &cs0);
                sincosf((float)row * if1, &sn1, &cs1);
                float o0 = v0 * cs0 + v2 * sn0;
                float o2 = v2 * cs0 - v0 * sn0;
                float o1 = v1 * cs1 + v3 * sn1;
                float o3 = v3 * cs1 - v1 * sn1;
                v0 = o0; v1 = o1; v2 = o2; v3 = o3;
            }
            size_t base = ((size_t)h * S_ + row) * HD_;
            dst[base +      ml] = f2bf(v0);
            dst[base + 16 + ml] = f2bf(v1);
            dst[base + 32 + ml] = f2bf(v2);
            dst[base + 48 + ml] = f2bf(v3);
        }
    }
}

// ---------------------------------------------------------------------------
// MFMA bf16 flash attention, double-buffered LDS + async reg staging.
// Bounded-score softmax: q,k are l2-normalized and q pre-scaled by 0.125, so
// |s| <= 0.125 ALWAYS (Cauchy-Schwarz) -> exp(s) in [0.88,1.13]; no online
// max / rescale needed. Row sums accumulate per-lane; one shuffle reduce at
// the end. Mathematically identical to max-subtracted softmax.
// ---------------------------------------------------------------------------
#define FS 72   // shorts per LDS row (pad: 144B rows -> 2-way banks, free)
__global__ __launch_bounds__(256) void flash_attn_mfma_kernel(
    const unsigned short* __restrict__ qh, const unsigned short* __restrict__ khb,
    const unsigned short* __restrict__ vhT, unsigned short* __restrict__ aob)
{
    __shared__ __align__(16) short Ks[2][64][FS];
    __shared__ __align__(16) short Vs[2][64][FS];   // [buf][d][token]
    __shared__ __align__(16) short Ps[4][16][FS];   // per-wave scratch
    int u = blockIdx.x & 255;
    int v = blockIdx.x >> 8;
    int h = u & 15;
    int p = u >> 4;
    int t = v ? (31 - p) : p;
    int tid = threadIdx.x;
    int wq = tid >> 6;
    int lane = tid & 63;
    int ml = lane & 15, quad = lane >> 4;
    int srow = tid >> 2;          // 0..63
    int sc = (tid & 3) * 16;      // 0,16,32,48 (shorts)
    const unsigned short* Qb = qh  + (size_t)h * S_ * HD_;
    const unsigned short* Kb = khb + (size_t)h * S_ * HD_;
    const unsigned short* Vt = vhT + (size_t)h * HD_ * S_;

    int q0 = t * 64;
    int qrow = q0 + wq * 16 + ml;
    s16x8 aq0 = *(const s16x8*)(Qb + (size_t)qrow * HD_ + quad * 8);
    s16x8 aq1 = *(const s16x8*)(Qb + (size_t)qrow * HD_ + 32 + quad * 8);

    float ps[4];                  // per-lane partial row sums
    f32x4 o[4];
#pragma unroll
    for (int r = 0; r < 4; r++) ps[r] = 0.f;
#pragma unroll
    for (int nb = 0; nb < 4; nb++) o[nb] = (f32x4){0.f, 0.f, 0.f, 0.f};

    int4 kr0, kr1, vr0, vr1;      // staging registers
    // prologue: tile 0 -> buf 0
    {
        const unsigned short* kp = Kb + (size_t)srow * HD_ + sc;
        kr0 = *(const int4*)kp; kr1 = *(const int4*)(kp + 8);
        const unsigned short* vp = Vt + (size_t)srow * S_ + sc;
        vr0 = *(const int4*)vp; vr1 = *(const int4*)(vp + 8);
        *(int4*)(&Ks[0][srow][sc]) = kr0; *(int4*)(&Ks[0][srow][sc + 8]) = kr1;
        *(int4*)(&Vs[0][srow][sc]) = vr0; *(int4*)(&Vs[0][srow][sc + 8]) = vr1;
    }
    __syncthreads();
    int cur = 0;

    for (int kt = 0; kt <= t; kt++) {
        int k0 = kt * 64;
        // issue next tile's global loads early (latency hides under compute)
        if (kt < t) {
            const unsigned short* kp = Kb + (size_t)(k0 + 64 + srow) * HD_ + sc;
            kr0 = *(const int4*)kp; kr1 = *(const int4*)(kp + 8);
            const unsigned short* vp = Vt + (size_t)srow * S_ + k0 + 64 + sc;
            vr0 = *(const int4*)vp; vr1 = *(const int4*)(vp + 8);
        }

        f32x4 s[4];
#pragma unroll
        for (int nb = 0; nb < 4; nb++) s[nb] = (f32x4){0.f, 0.f, 0.f, 0.f};
        __builtin_amdgcn_s_setprio(1);
#pragma unroll
        for (int nb = 0; nb < 4; nb++) {
            s16x8 b0 = *(const s16x8*)(&Ks[cur][nb * 16 + ml][quad * 8]);
            s16x8 b1 = *(const s16x8*)(&Ks[cur][nb * 16 + ml][32 + quad * 8]);
            s[nb] = __builtin_amdgcn_mfma_f32_16x16x32_bf16(aq0, b0, s[nb], 0, 0, 0);
            s[nb] = __builtin_amdgcn_mfma_f32_16x16x32_bf16(aq1, b1, s[nb], 0, 0, 0);
        }
        __builtin_amdgcn_s_setprio(0);

        // P = exp(S) (bounded, no max needed); masked -> 0; per-lane row sums
#pragma unroll
        for (int nb = 0; nb < 4; nb++)
#pragma unroll
            for (int r = 0; r < 4; r++) {
                float pe = __expf(s[nb][r]);
                if (kt == t && (nb * 16 + ml) > (wq * 16 + quad * 4 + r))
                    pe = 0.f;
                ps[r] += pe;
                Ps[wq][quad * 4 + r][nb * 16 + ml] = (short)f2bf(pe);
            }

        s16x8 ap0 = *(const s16x8*)(&Ps[wq][ml][quad * 8]);
        s16x8 ap1 = *(const s16x8*)(&Ps[wq][ml][32 + quad * 8]);
        __builtin_amdgcn_s_setprio(1);
#pragma unroll
        for (int nb = 0; nb < 4; nb++) {
            s16x8 b0 = *(const s16x8*)(&Vs[cur][nb * 16 + ml][quad * 8]);
            s16x8 b1 = *(const s16x8*)(&Vs[cur][nb * 16 + ml][32 + quad * 8]);
            o[nb] = __builtin_amdgcn_mfma_f32_16x16x32_bf16(ap0, b0, o[nb], 0, 0, 0);
            o[nb] = __builtin_amdgcn_mfma_f32_16x16x32_bf16(ap1, b1, o[nb], 0, 0, 0);
        }
        __builtin_amdgcn_s_setprio(0);

        __syncthreads();                       // B1: reads of buf[cur] done
        if (kt < t) {
            *(int4*)(&Ks[cur ^ 1][srow][sc])     = kr0;
            *(int4*)(&Ks[cur ^ 1][srow][sc + 8]) = kr1;
            *(int4*)(&Vs[cur ^ 1][srow][sc])     = vr0;
            *(int4*)(&Vs[cur ^ 1][srow][sc + 8]) = vr1;
            __syncthreads();                   // B2: buf[cur^1] visible
            cur ^= 1;
        }
    }

    // final: reduce row sums over the 16 ml lanes (same quad), normalize.
#pragma unroll
    for (int r = 0; r < 4; r++) {
        float l = ps[r];
#pragma unroll
        for (int off = 1; off < 16; off <<= 1)
            l += __shfl_xor(l, off);
        float inv = 1.0f / l;
        int row = q0 + wq * 16 + quad * 4 + r;
#pragma unroll
        for (int nb = 0; nb < 4; nb++)
            aob[(size_t)row * D_ + h * HD_ + nb * 16 + ml] =
                f2bf(o[nb][r] * inv);
    }
}

// ---------------------------------------------------------------------------
// expert score GEMM, split-K x8: block = (chunk c, k-slice sk).
// ---------------------------------------------------------------------------
__global__ __launch_bounds__(256) void score_gemm_kernel(
    const unsigned short* __restrict__ xfb, const unsigned short* __restrict__ kgath,
    float* __restrict__ msbufp)
{
    __shared__ __align__(16) short As[128][32];
    __shared__ __align__(16) short Bs[128][32];
    int c  = blockIdx.x >> 3;
    int sk = blockIdx.x & 7;
    const unsigned short* A  = xfb   + (size_t)c * 128 * D_ + sk * 128;
    const unsigned short* Bt = kgath + (size_t)c * 128 * D_ + sk * 128;
    int tid = threadIdx.x;
    int wave = tid >> 6, lane = tid & 63;
    int ml = lane & 15, q = lane >> 4;
    int wr = wave >> 1, wc = wave & 1;
    int srow = tid >> 2;
    int scol = (tid & 3) * 8;

    f32x4 acc[4][4];
#pragma unroll
    for (int i = 0; i < 4; i++)
#pragma unroll
        for (int j = 0; j < 4; j++) acc[i][j] = (f32x4){0.f, 0.f, 0.f, 0.f};

    const unsigned short* Ap = A  + (size_t)srow * D_ + scol;
    const unsigned short* Bp = Bt + (size_t)srow * D_ + scol;
    short* ldsA0 = &As[wave * 16][0];
    short* ldsA1 = &As[64 + wave * 16][0];
    short* ldsB0 = &Bs[wave * 16][0];
    short* ldsB1 = &Bs[64 + wave * 16][0];

    for (int k0 = 0; k0 < 128; k0 += 32) {
        __syncthreads();
        GLOAD16(Ap + k0, ldsA0);
        GLOAD16(Ap + (size_t)64 * D_ + k0, ldsA1);
        GLOAD16(Bp + k0, ldsB0);
        GLOAD16(Bp + (size_t)64 * D_ + k0, ldsB1);
        __syncthreads();

        s16x8 af[4], bf[4];
#pragma unroll
        for (int i = 0; i < 4; i++)
            af[i] = *(const s16x8*)(&As[wr * 64 + i * 16 + ml][q * 8]);
#pragma unroll
        for (int j = 0; j < 4; j++)
            bf[j] = *(const s16x8*)(&Bs[wc * 64 + j * 16 + ml][q * 8]);
#pragma unroll
        for (int i = 0; i < 4; i++)
#pragma unroll
            for (int j = 0; j < 4; j++)
                acc[i][j] = __builtin_amdgcn_mfma_f32_16x16x32_bf16(
                    af[i], bf[j], acc[i][j], 0, 0, 0);
    }

    float* out = msbufp + (size_t)blockIdx.x * 128 * 128;
#pragma unroll
    for (int i = 0; i < 4; i++)
#pragma unroll
        for (int j = 0; j < 4; j++) {
            int col = wc * 64 + j * 16 + ml;
#pragma unroll
            for (int r = 0; r < 4; r++) {
                int row = wr * 64 + i * 16 + q * 4 + r;
                out[(size_t)row * 128 + col] = acc[i][j][r];
            }
        }
}

// ---------------------------------------------------------------------------
// MoE with rank-1 experts + fused combine weights; 4 tokens per block so the
// chunk-shared expert vectors (w0/w1/w2) are read once per 4 tokens.
//   512 blocks = (chunk c, token-group g of 4).
// ---------------------------------------------------------------------------
__global__ __launch_bounds__(256) void moe_kernel(
    const float* __restrict__ xf, const float* __restrict__ xfi,
    const int* __restrict__ indices, const float* __restrict__ msbufp,
    const float* __restrict__ scores,
    const float* __restrict__ score_probs, const float* __restrict__ head_probs,
    const float* __restrict__ experts, float* __restrict__ out)
{
    int g = blockIdx.x, tid = threadIdx.x;
    int c = g >> 5;
    int t0 = c * NT_ + (g & 31) * 4;
    __shared__ int sidx[ET_];
    __shared__ float sw[4][ET_];
    __shared__ float sact[4][ET_];
    __shared__ float sx[4][D_];
    if (tid < ET_) sidx[tid] = indices[c * ET_ + tid];
#pragma unroll
    for (int tt = 0; tt < 4; tt++)
        ((float4*)sx[tt])[tid] =
            ((const float4*)(xf + (size_t)(t0 + tt) * D_))[tid];
    // ---- phase A: combine weights; thread = (e = tid>>4, hh = tid&15) ----
    {
        int e = tid >> 4, hh = tid & 15;
        int idxe = indices[c * ET_ + e];
        int rr = e >> 2;   // e / DE_
        float sp0 = score_probs[((size_t)rr * E_ + idxe) * H_ + hh];
        float sp1 = score_probs[((size_t)(RE_ + rr) * E_ + idxe) * H_ + hh];
        float hp  = head_probs[((size_t)rr * E_ + idxe) * H_ + hh];
#pragma unroll
        for (int tt = 0; tt < 4; tt++) {
            int t = t0 + tt;
            int trow = t & 127;
            const float* mp = msbufp + ((size_t)(c * 8) * 128 + trow) * 128
                                     + e * 8 + (hh >> 1);
            float ms = 0.f;
#pragma unroll
            for (int sck = 0; sck < 8; sck++)
                ms += mp[(size_t)sck * 128 * 128];
            float scv = scores[(size_t)t * (ET_ * H_) + tid];
            float z = sp0 * ms + sp1 * scv;
            float term = hp / (1.0f + __expf(-z));
#pragma unroll
            for (int off = 1; off < 16; off <<= 1)
                term += __shfl_xor(term, off);
            if (hh == 0) sw[tt][e] = term;
        }
    }
    __syncthreads();   // sx, sw, sidx ready

    // ---- phase B: wave wv computes h0/h1/act for experts 4wv..4wv+3 ----
    int wv = tid >> 6, lane = tid & 63;
#pragma unroll
    for (int ee = 0; ee < 4; ee++) {
        int e = wv * 4 + ee;
        int idx = sidx[e];
        size_t base = (size_t)idx * D_;
        float p0[4] = {0.f, 0.f, 0.f, 0.f};
        float p1[4] = {0.f, 0.f, 0.f, 0.f};
#pragma unroll
        for (int rr = 0; rr < 4; rr++) {
            int dd = rr * 256 + lane * 4;
            float4 w0 = *(const float4*)(experts + base + dd);
            float4 w1 = *(const float4*)(experts + (size_t)E_ * D_ + base + dd);
#pragma unroll
            for (int tt = 0; tt < 4; tt++) {
                float4 xr = *(const float4*)(&sx[tt][dd]);
                p0[tt] += xr.x*w0.x + xr.y*w0.y + xr.z*w0.z + xr.w*w0.w;
                p1[tt] += xr.x*w1.x + xr.y*w1.y + xr.z*w1.z + xr.w*w1.w;
            }
        }
#pragma unroll
        for (int tt = 0; tt < 4; tt++) {
#pragma unroll
            for (int off = 32; off > 0; off >>= 1) {
                p0[tt] += __shfl_xor(p0[tt], off);
                p1[tt] += __shfl_xor(p1[tt], off);
            }
        }
        if (lane == 0) {
#pragma unroll
            for (int tt = 0; tt < 4; tt++)
                sact[tt][e] = p0[tt] / (1.0f + __expf(-p0[tt])) * p1[tt]
                              * sw[tt][e];
        }
    }
    __syncthreads();   // sact ready

    // ---- phase C: accumulate w2, amortized over 4 tokens ----
    float4 a0 = {0,0,0,0}, a1 = {0,0,0,0}, a2 = {0,0,0,0}, a3 = {0,0,0,0};
    const float* w2base = experts + (size_t)2 * E_ * D_;
#pragma unroll
    for (int e = 0; e < ET_; e++) {
        float4 w2 = *(const float4*)(w2base + (size_t)sidx[e] * D_ + tid * 4);
        float c0 = sact[0][e], c1 = sact[1][e], c2 = sact[2][e], c3 = sact[3][e];
        a0.x += c0 * w2.x; a0.y += c0 * w2.y; a0.z += c0 * w2.z; a0.w += c0 * w2.w;
        a1.x += c1 * w2.x; a1.y += c1 * w2.y; a1.z += c1 * w2.z; a1.w += c1 * w2.w;
        a2.x += c2 * w2.x; a2.y += c2 * w2.y; a2.z += c2 * w2.z; a2.w += c2 * w2.w;
        a3.x += c3 * w2.x; a3.y += c3 * w2.y; a3.z += c3 * w2.z; a3.w += c3 * w2.w;
    }
#pragma unroll
    for (int tt = 0; tt < 4; tt++) {
        float4 av = (tt == 0) ? a0 : (tt == 1) ? a1 : (tt == 2) ? a2 : a3;
        size_t o = (size_t)(t0 + tt) * D_ + tid * 4;
        float4 rv = *(const float4*)(xfi + o);
        float4 ov;
        ov.x = av.x + rv.x;
        ov.y = av.y + rv.y;
        ov.z = av.z + rv.z;
        ov.w = av.w + rv.w;
        *(float4*)(out + o) = ov;
    }
}

// ---------------------------------------------------------------------------
extern "C" void kernel_launch(void* const* d_in, const int* in_sizes, int n_in,
                              void* d_out, int out_size, void* d_ws, size_t ws_size,
                              hipStream_t stream)
{
    (void)in_sizes; (void)n_in; (void)out_size; (void)ws_size;
    const float* x_input     = (const float*)d_in[0];
    const int*   indices     = (const int*)d_in[1];
    const float* scores      = (const float*)d_in[2];
    const float* attn_w      = (const float*)d_in[3];
    const float* attn_out_w  = (const float*)d_in[4];
    const float* attn_norm_w = (const float*)d_in[5];
    const float* ffn_norm_w  = (const float*)d_in[6];
    const float* ffn_experts = (const float*)d_in[7];
    const float* keys        = (const float*)d_in[8];
    const float* head_probs  = (const float*)d_in[9];
    const float* score_probs = (const float*)d_in[10];
    float* out = (float*)d_out;

    float* ws = (float*)d_ws;
    const size_t MF = 1024 * 1024;
    // Region map (floats), peak 14M floats = 56 MB:
    // qh    [0,1M)    bf16     (gemm_qkv -> flash)
    // khb   [1M,2M)   bf16
    // vhb   [2M,3M)   bf16     (gemm_qkv -> transpose_v)
    // vhT   [3M,4M)   bf16     (transpose_v -> flash)
    // xfi   [4M,6M)   f32      (gemm2 -> rmsnorm_dual, moe)
    // xnb   [6M,7M)   bf16     (preprocess -> gemm_qkv); reused: aob (flash->gemm2)
    // woutT [7M,7.5M) bf16     (preprocess -> gemm2)
    // wqkvT [8M,9.5M) bf16     (preprocess -> gemm_qkv); reused: xf [8M,10M) f32
    // kgath [10M,11M) bf16     (preprocess -> score_gemm)
    // xfb   [11M,12M) bf16     (rmsnorm_dual -> score_gemm)
    // msbufp[12M,14M) f32      (score_gemm -> moe)
    unsigned short* qh    = (unsigned short*)ws;
    unsigned short* khb   = (unsigned short*)(ws + 1 * MF);
    unsigned short* vhb   = (unsigned short*)(ws + 2 * MF);
    unsigned short* vhT   = (unsigned short*)(ws + 3 * MF);
    float* xfi            = ws + 4 * MF;
    unsigned short* xnb   = (unsigned short*)(ws + 6 * MF);
    unsigned short* aob   = (unsigned short*)(ws + 6 * MF);
    unsigned short* woutT = (unsigned short*)(ws + 7 * MF);
    unsigned short* wqkvT = (unsigned short*)(ws + 8 * MF);
    float* xf             = ws + 8 * MF;
    unsigned short* kgath = (unsigned short*)(ws + 10 * MF);
    unsigned short* xfb   = (unsigned short*)(ws + 11 * MF);
    float* msbufp         = ws + 12 * MF;

    // 1) mega-preprocess: rmsnorm + weight transposes + key gather
    preprocess_kernel<<<8192, 256, 0, stream>>>(
        x_input, attn_norm_w, xnb, attn_w, wqkvT, attn_out_w, woutT,
        keys, indices, kgath);

    // 2) fused qkv GEMM + l2norm + rope + head split -> qh/khb/vhb bf16
    {
        dim3 g(3 * D_ / 128, T_ / 128);
        mfma_gemm_qkv_kernel<<<g, 256, 0, stream>>>(xnb, wqkvT, qh, khb, vhb);
    }

    // 3) transpose V: vhb [h][s][d] -> vhT [h][d][s]
    {
        dim3 g(HD_ / 32, S_ / 32, NH_);
        transpose_v_kernel<<<g, 256, 0, stream>>>(vhb, vhT);
    }

    // 4) MFMA flash attention (bounded-score softmax) -> aob bf16
    flash_attn_mfma_kernel<<<(S_ / 64) * NH_, 256, 0, stream>>>(qh, khb, vhT, aob);

    // 5) xfi = aob @ attn_out_w + x_input   (MFMA + residual)
    {
        dim3 g(D_ / 128, T_ / 128);
        mfma_gemm_kernel<1><<<g, 256, 0, stream>>>(aob, woutT, x_input, xfi,
                                                   T_, D_, D_);
    }

    // 6) rmsnorm dual: xf fp32 + xfb bf16
    rmsnorm_dual_kernel<<<T_, 256, 0, stream>>>(xfi, ffn_norm_w, xf, xfb);

    // 7) expert score GEMM, split-K x8 -> msbufp partials
    score_gemm_kernel<<<BC_ * 8, 256, 0, stream>>>(xfb, kgath, msbufp);

    // 8) MoE (4 tokens/block, combine weights fused) + final residual
    moe_kernel<<<T_ / 4, 256, 0, stream>>>(xf, xfi, indices, msbufp, scores,
                                           score_probs, head_probs,
                                           ffn_experts, out);
}